// Round 7
// baseline (478.730 us; speedup 1.0000x reference)
//
#include <hip/hip_runtime.h>

typedef __attribute__((ext_vector_type(8))) short bf16x8;
typedef __attribute__((ext_vector_type(4))) float f32x4;

#define CCH 32   // chunks over L
#define TCH 64   // chunk length

// ---------- bf16 helpers (round-to-nearest-even) ----------
__device__ __forceinline__ unsigned short f2b(float f) {
    unsigned u = __float_as_uint(f);
    return (unsigned short)((u + 0x7fffu + ((u >> 16) & 1u)) >> 16);
}
__device__ __forceinline__ float b2f(unsigned short h) {
    return __uint_as_float(((unsigned)h) << 16);
}
__device__ __forceinline__ float softplus_f(float z) {
    return (z > 15.f) ? z : __logf(1.f + __expf(z));
}
__device__ __forceinline__ float silu_f(float g) {
    return g / (1.f + __expf(-g));
}

// async 16B/lane global->LDS (lds dst = wave-uniform base + lane*16)
__device__ __forceinline__ void gload16(const unsigned short* g, unsigned short* l) {
    __builtin_amdgcn_global_load_lds(
        (const __attribute__((address_space(1))) void*)g,
        (__attribute__((address_space(3))) void*)l, 16, 0, 0);
}

// ---------- fused fp32 -> bf16 cast for all 5 tensors ----------
__global__ __launch_bounds__(256)
void cast_all(const float* __restrict__ h, const float* __restrict__ win,
              const float* __restrict__ wx, const float* __restrict__ wdt,
              const float* __restrict__ wout,
              unsigned short* __restrict__ dh, unsigned short* __restrict__ dwin,
              unsigned short* __restrict__ dwx, unsigned short* __restrict__ dwdt,
              unsigned short* __restrict__ dwout) {
    const int n0 = 1572864, n1 = n0 + 2359296, n2 = n1 + 98304,
              n3 = n2 + 73728, n4 = n3 + 1179648;
    int i = blockIdx.x * 256 + threadIdx.x;
    const float* s; unsigned short* d; int off;
    if (i < n0)      { s = h;    d = dh;    off = i; }
    else if (i < n1) { s = win;  d = dwin;  off = i - n0; }
    else if (i < n2) { s = wx;   d = dwx;   off = i - n1; }
    else if (i < n3) { s = wdt;  d = dwdt;  off = i - n2; }
    else if (i < n4) { s = wout; d = dwout; off = i - n3; }
    else return;
    float4 v = reinterpret_cast<const float4*>(s)[off];
    ushort4 o;
    o.x = f2b(v.x); o.y = f2b(v.y); o.z = f2b(v.z); o.w = f2b(v.w);
    reinterpret_cast<ushort4*>(d)[off] = o;
}

// ============================================================================
// in_proj GEMM: 256M x 384N tile, grid EXACTLY 256 blocks (16 M x 16 N, one
// full round on 256 CUs), BK=32, K=1536 = 48 K-tiles, bf16 out with silu on
// cols >= silu_col0.  512 thr = 8 waves (2M x 4N): per-wave C = 128x96 =
// 8x6 frags -> acc 192 VGPR; fb[6]=24 + fa pair=8 live -> ~240 peak, pinned
// by __launch_bounds__(512,2) (256-VGPR budget).  LDS 80 KiB dbuf (A 2x16K,
// B 2x24K), free-running body, per-tile vmcnt(0).  4-slot XOR swizzle
// (slot ^= row&3; 2-way bank alias = free) with pre-swizzled global source.
// XCD mapping: XCD c owns 2 col-tiles (768-col B-stripe = 2.3 MB, L2-res).
// ============================================================================
__global__ __launch_bounds__(512, 2)
void gemm_in(const unsigned short* __restrict__ A, const unsigned short* __restrict__ W,
             unsigned short* __restrict__ Cout, int Kc, int lda, int ldw, int ldc,
             int silu_col0) {
    __shared__ __align__(16) unsigned short A0s[8192];    // [256][32] bf16
    __shared__ __align__(16) unsigned short B0s[12288];   // [384][32] bf16
    __shared__ __align__(16) unsigned short A1s[8192];
    __shared__ __align__(16) unsigned short B1s[12288];
    const int tid  = threadIdx.x;
    const int lane = tid & 63;
    const int wave = tid >> 6;
    const int wr   = wave >> 2;    // 0..1 (128-row half)
    const int wc   = wave & 3;     // 0..3 (96-col group)
    const int lr   = lane & 15;
    const int quad = lane >> 4;    // frag k-slot (0..3)
    const int sw2  = lr & 3;       // read XOR over 4 slots

    // 256 blocks: c = XCD, owns col-tiles c*2 and c*2+1
    const int c  = blockIdx.x & 7;
    const int j  = blockIdx.x >> 3;          // 0..31
    const int bn = (c * 2 + (j & 1)) * 384;
    const int bm = (j >> 1) * 256;

    // staging: 4 lanes/row (16B), 16 rows/wave/op; global col pre-swizzled
    const int rsub = wave * 16 + (lane >> 2);
    const int csw  = ((lane & 3) ^ ((lane >> 2) & 3)) * 8;
    const unsigned short* gA = A + (size_t)(bm + rsub) * lda + csw;
    const unsigned short* gB = W + (size_t)(bn + rsub) * ldw + csw;

#define STAGE_A(ARR, kt) do { \
        gload16(gA + (size_t)0   * lda + (kt) * 32, ARR + wave * 512); \
        gload16(gA + (size_t)128 * lda + (kt) * 32, ARR + 4096 + wave * 512); \
    } while (0)
#define STAGE_B(ARR, kt) do { \
        gload16(gB + (size_t)0   * ldw + (kt) * 32, ARR + wave * 512); \
        gload16(gB + (size_t)128 * ldw + (kt) * 32, ARR + 4096 + wave * 512); \
        gload16(gB + (size_t)256 * ldw + (kt) * 32, ARR + 8192 + wave * 512); \
    } while (0)

    // frag reads: row*32 elems + (quad ^ (row&3))*8; row&3 == lr&3 here
#define LDA_F(ARR, mi) \
    (*reinterpret_cast<const bf16x8*>(&ARR[(wr * 128 + (mi) * 16 + lr) * 32 + ((quad ^ sw2)) * 8]))
#define LDB_F(ARR, ni) \
    (*reinterpret_cast<const bf16x8*>(&ARR[(wc * 96 + (ni) * 16 + lr) * 32 + ((quad ^ sw2)) * 8]))

#define PRIO1 __builtin_amdgcn_s_setprio(1)
#define PRIO0 __builtin_amdgcn_s_setprio(0)
#define VM0B  asm volatile("s_waitcnt vmcnt(0)\n\ts_barrier" ::: "memory")

    // body: fb[6] once, then 4 fa-pairs, 12 MFMA each (acc liveness capped)
#define TILE_BODY(AX, BX) do { \
        _Pragma("unroll") for (int ni = 0; ni < 6; ++ni) fb[ni] = LDB_F(BX, ni); \
        _Pragma("unroll") for (int mp = 0; mp < 4; ++mp) { \
            bf16x8 fa0 = LDA_F(AX, 2 * mp); \
            bf16x8 fa1 = LDA_F(AX, 2 * mp + 1); \
            PRIO1; \
            _Pragma("unroll") for (int ni = 0; ni < 6; ++ni) { \
                acc[2 * mp][ni]     = __builtin_amdgcn_mfma_f32_16x16x32_bf16(fa0, fb[ni], acc[2 * mp][ni], 0, 0, 0); \
                acc[2 * mp + 1][ni] = __builtin_amdgcn_mfma_f32_16x16x32_bf16(fa1, fb[ni], acc[2 * mp + 1][ni], 0, 0, 0); } \
            PRIO0; } \
    } while (0)

    f32x4 acc[8][6];
    const f32x4 zero = {0.f, 0.f, 0.f, 0.f};
#pragma unroll
    for (int m = 0; m < 8; ++m)
#pragma unroll
        for (int n = 0; n < 6; ++n) acc[m][n] = zero;

    bf16x8 fb[6];

    const int nkt = Kc >> 5;   // 48 (even)

    STAGE_A(A0s, 0); STAGE_B(B0s, 0);
    VM0B;

#pragma unroll 1
    for (int t = 0; t < nkt; t += 2) {
        if (t + 1 < nkt) { STAGE_A(A1s, t + 1); STAGE_B(B1s, t + 1); }
        TILE_BODY(A0s, B0s);
        VM0B;
        if (t + 1 < nkt) {
            if (t + 2 < nkt) { STAGE_A(A0s, t + 2); STAGE_B(B0s, t + 2); }
            TILE_BODY(A1s, B1s);
            VM0B;
        }
    }

    // C-write: row = bm + wr*128 + mi*16 + quad*4 + reg; col = bn + wc*96 + ni*16 + lr
#pragma unroll
    for (int mi = 0; mi < 8; ++mi) {
        const int row0 = bm + wr * 128 + mi * 16 + quad * 4;
#pragma unroll
        for (int ni = 0; ni < 6; ++ni) {
            const int col = bn + wc * 96 + ni * 16 + lr;
#pragma unroll
            for (int reg = 0; reg < 4; ++reg) {
                float v = acc[mi][ni][reg];
                if (col >= silu_col0) v = silu_f(v);
                Cout[(size_t)(row0 + reg) * ldc + col] = f2b(v);
            }
        }
    }
#undef STAGE_A
#undef STAGE_B
#undef LDA_F
#undef LDB_F
#undef PRIO1
#undef PRIO0
#undef VM0B
#undef TILE_BODY
}

// ============================================================================
// out_proj GEMM: 128M x 192N tile, grid EXACTLY 256 blocks, K=3072 single
// pass, fp32 direct to d_out (r6 version, measured best).
// ============================================================================
__global__ __launch_bounds__(512)
void gemm_out(const unsigned short* __restrict__ A, const unsigned short* __restrict__ W,
              float* __restrict__ Cout, int Kc, int lda, int ldw, int ldc) {
    __shared__ __align__(16) unsigned short A0s[8192];    // 128x64 bf16
    __shared__ __align__(16) unsigned short B0s[12288];   // 192x64 bf16
    __shared__ __align__(16) unsigned short A1s[8192];
    __shared__ __align__(16) unsigned short B1s[12288];
    const int tid  = threadIdx.x;
    const int lane = tid & 63;
    const int wave = tid >> 6;
    const int wr   = wave >> 2;    // 0..1 (64-row half)
    const int wc   = wave & 3;     // 0..3 (48-col group)
    const int lr   = lane & 15;
    const int quad = lane >> 4;
    const int sw   = lr & 7;

    // grid 256 = 8 XCD col-stripes x 32 M-tiles
    const int c  = blockIdx.x & 7;
    const int j  = blockIdx.x >> 3;   // 0..31
    const int bm = j * 128;
    const int bn = c * 192;

    const int rsub = wave * 8 + (lane >> 3);
    const int csw  = ((lane & 7) ^ ((lane >> 3) & 7)) * 8;
    const unsigned short* gA = A + (size_t)(bm + rsub) * lda + csw;
    const unsigned short* gB = W + (size_t)(bn + rsub) * ldw + csw;

#define STAGE_A(ARR, kt) do { \
        gload16(gA + (size_t)0  * lda + (kt) * 64, ARR + 0    + wave * 512); \
        gload16(gA + (size_t)64 * lda + (kt) * 64, ARR + 4096 + wave * 512); \
    } while (0)
#define STAGE_B(ARR, kt) do { \
        gload16(gB + (size_t)0   * ldw + (kt) * 64, ARR + 0    + wave * 512); \
        gload16(gB + (size_t)64  * ldw + (kt) * 64, ARR + 4096 + wave * 512); \
        gload16(gB + (size_t)128 * ldw + (kt) * 64, ARR + 8192 + wave * 512); \
    } while (0)

#define LDA_F(ARR, mi, kk) \
    (*reinterpret_cast<const bf16x8*>(&ARR[(wr * 64 + (mi) * 16 + lr) * 64 + (((((kk) << 2) | quad)) ^ sw) * 8]))
#define LDB_F(ARR, ni, kk) \
    (*reinterpret_cast<const bf16x8*>(&ARR[(wc * 48 + (ni) * 16 + lr) * 64 + (((((kk) << 2) | quad)) ^ sw) * 8]))

#define PRIO1 __builtin_amdgcn_s_setprio(1)
#define PRIO0 __builtin_amdgcn_s_setprio(0)
#define VM0B  asm volatile("s_waitcnt vmcnt(0)\n\ts_barrier" ::: "memory")

#define TILE_BODY(AX, BX) do { \
        _Pragma("unroll") for (int ni = 0; ni < 3; ++ni) { \
            fb[ni][0] = LDB_F(BX, ni, 0); fb[ni][1] = LDB_F(BX, ni, 1); } \
        _Pragma("unroll") for (int mi = 0; mi < 4; ++mi) { \
            fa[mi][0] = LDA_F(AX, mi, 0); fa[mi][1] = LDA_F(AX, mi, 1); } \
        PRIO1; \
        _Pragma("unroll") for (int mi = 0; mi < 4; ++mi) \
        _Pragma("unroll") for (int ni = 0; ni < 3; ++ni) { \
            acc[mi][ni] = __builtin_amdgcn_mfma_f32_16x16x32_bf16(fa[mi][0], fb[ni][0], acc[mi][ni], 0, 0, 0); \
            acc[mi][ni] = __builtin_amdgcn_mfma_f32_16x16x32_bf16(fa[mi][1], fb[ni][1], acc[mi][ni], 0, 0, 0); } \
        PRIO0; \
    } while (0)

    f32x4 acc[4][3];
    const f32x4 zero = {0.f, 0.f, 0.f, 0.f};
#pragma unroll
    for (int m = 0; m < 4; ++m)
#pragma unroll
        for (int n = 0; n < 3; ++n) acc[m][n] = zero;

    bf16x8 fa[4][2], fb[3][2];

    const int nkt = Kc >> 6;   // 48 (even)

    STAGE_A(A0s, 0); STAGE_B(B0s, 0);
    VM0B;

#pragma unroll 1
    for (int t = 0; t < nkt; t += 2) {
        if (t + 1 < nkt) { STAGE_A(A1s, t + 1); STAGE_B(B1s, t + 1); }
        TILE_BODY(A0s, B0s);
        VM0B;
        if (t + 1 < nkt) {
            if (t + 2 < nkt) { STAGE_A(A0s, t + 2); STAGE_B(B0s, t + 2); }
            TILE_BODY(A1s, B1s);
            VM0B;
        }
    }

#pragma unroll
    for (int mi = 0; mi < 4; ++mi) {
        const int row0 = bm + wr * 64 + mi * 16 + quad * 4;
#pragma unroll
        for (int ni = 0; ni < 3; ++ni) {
            const int col = bn + wc * 48 + ni * 16 + lr;
#pragma unroll
            for (int reg = 0; reg < 4; ++reg)
                Cout[(size_t)(row0 + reg) * ldc + col] = acc[mi][ni][reg];
        }
    }
#undef STAGE_A
#undef STAGE_B
#undef LDA_F
#undef LDB_F
#undef PRIO1
#undef PRIO0
#undef VM0B
#undef TILE_BODY
}

// ---------- MFMA GEMM, 3-stage pipelined async LDS staging (128x128) ----------
// kept for x_proj (N=128) and dt_proj (K=96).
// OP=0: fp32 store (+ split-K z, C offset kz*czs)
// OP=3: bf16 store of softplus(acc + bias[col])
template <int OP>
__global__ __launch_bounds__(256)
void gemm_mfma(const unsigned short* __restrict__ A, const unsigned short* __restrict__ W,
               void* __restrict__ Cout, int Kc, int lda, int ldw, int ldc,
               const float* __restrict__ bias, int silu_col0, long long czs) {
    __shared__ unsigned short As[3][4096];   // 3 x 128x32 bf16 = 24 KB
    __shared__ unsigned short Bs[3][4096];
    const int tid = threadIdx.x;
    const int bm = blockIdx.y * 128;
    const int bn = blockIdx.x * 128;
    const int kz = blockIdx.z;
    A += (size_t)kz * Kc;
    W += (size_t)kz * Kc;
    const int lane = tid & 63;
    const int wave = tid >> 6;
    const int r_a = lane >> 2;          // row within 16-row chunk
    const int k8 = (lane & 3) * 8;      // k offset (8 bf16 = 16B)

    const unsigned short* gA0 = A + (size_t)(bm + wave * 16 + r_a) * lda + k8;
    const unsigned short* gA1 = A + (size_t)(bm + 64 + wave * 16 + r_a) * lda + k8;
    const unsigned short* gB0 = W + (size_t)(bn + wave * 16 + r_a) * ldw + k8;
    const unsigned short* gB1 = W + (size_t)(bn + 64 + wave * 16 + r_a) * ldw + k8;

    const int wm = (wave & 1) * 64;
    const int wn = (wave >> 1) * 64;
    const int lr = lane & 15;
    const int quad = lane >> 4;

    f32x4 acc[4][4];
    const f32x4 zero = {0.f, 0.f, 0.f, 0.f};
#pragma unroll
    for (int i = 0; i < 4; i++)
#pragma unroll
        for (int j = 0; j < 4; j++) acc[i][j] = zero;

#define STAGE(koff, j) do { \
        gload16(gA0 + (koff), As[j] + wave * 512); \
        gload16(gA1 + (koff), As[j] + (wave + 4) * 512); \
        gload16(gB0 + (koff), Bs[j] + wave * 512); \
        gload16(gB1 + (koff), Bs[j] + (wave + 4) * 512); \
    } while (0)

    const int niter = Kc >> 5;
    STAGE(0, 0);
    if (niter > 1) STAGE(32, 1);

    int ib = 0;   // LDS buffer holding tile k
    for (int k = 0; k < niter; k++) {
        if (k + 1 < niter)
            asm volatile("s_waitcnt vmcnt(4)\n\ts_barrier" ::: "memory");
        else
            asm volatile("s_waitcnt vmcnt(0)\n\ts_barrier" ::: "memory");
        if (k + 2 < niter) {
            int is_ = ib + 2; if (is_ >= 3) is_ -= 3;
            STAGE((k + 2) << 5, is_);
        }
        const unsigned short* as = As[ib];
        const unsigned short* bs = Bs[ib];
        bf16x8 fa[4], fb[4];
#pragma unroll
        for (int mi = 0; mi < 4; mi++)
            fa[mi] = *reinterpret_cast<const bf16x8*>(as + (wm + mi * 16 + lr) * 32 + quad * 8);
#pragma unroll
        for (int ni = 0; ni < 4; ni++)
            fb[ni] = *reinterpret_cast<const bf16x8*>(bs + (wn + ni * 16 + lr) * 32 + quad * 8);
#pragma unroll
        for (int mi = 0; mi < 4; mi++)
#pragma unroll
            for (int ni = 0; ni < 4; ni++)
                acc[mi][ni] = __builtin_amdgcn_mfma_f32_16x16x32_bf16(fa[mi], fb[ni], acc[mi][ni], 0, 0, 0);
        ib = (ib == 2) ? 0 : ib + 1;
    }
#undef STAGE

    // C/D layout: col = lane&15 (+16*ni), row = quad*4 + reg (+16*mi)
#pragma unroll
    for (int mi = 0; mi < 4; mi++)
#pragma unroll
        for (int reg = 0; reg < 4; reg++) {
            int row = bm + wm + mi * 16 + quad * 4 + reg;
#pragma unroll
            for (int ni = 0; ni < 4; ni++) {
                int col = bn + wn + ni * 16 + lr;
                float v = acc[mi][ni][reg];
                if (OP == 0) {
                    float* Cf = (float*)Cout + (size_t)kz * czs;
                    Cf[(size_t)row * ldc + col] = v;
                } else if (OP == 2) {
                    if (col >= silu_col0) v = silu_f(v);
                    ((unsigned short*)Cout)[(size_t)row * ldc + col] = f2b(v);
                } else {  // OP == 3
                    ((unsigned short*)Cout)[(size_t)row * ldc + col] = f2b(softplus_f(v + bias[col]));
                }
            }
        }
}

// ---------- split-K reduction for x_proj; fuses dtin bf16 extraction ----------
__global__ __launch_bounds__(256)
void reduce_xpart(const float* __restrict__ xpart, float* __restrict__ ssmp,
                  unsigned short* __restrict__ dtin) {
    const int BL = 4096;
    int idx = blockIdx.x * 256 + threadIdx.x;   // BL*32 threads
    int row = idx >> 5;
    int c4 = (idx & 31) * 4;
    float4 s = {0.f, 0.f, 0.f, 0.f};
#pragma unroll
    for (int z = 0; z < 8; z++) {
        float4 v = *reinterpret_cast<const float4*>(xpart + (size_t)z * BL * 128 + (size_t)row * 128 + c4);
        s.x += v.x; s.y += v.y; s.z += v.z; s.w += v.w;
    }
    *reinterpret_cast<float4*>(ssmp + (size_t)row * 128 + c4) = s;
    if (c4 < 96) {
        ushort4 o;
        o.x = f2b(s.x); o.y = f2b(s.y); o.z = f2b(s.z); o.w = f2b(s.w);
        *reinterpret_cast<ushort4*>(dtin + (size_t)row * 96 + c4) = o;
    }
}

// ---------- causal depthwise conv (K=4) + SiLU, 8 channels/thread ----------
__global__ __launch_bounds__(256)
void conv_silu8(const unsigned short* __restrict__ projbf, const float* __restrict__ cw,
                const float* __restrict__ cb, unsigned short* __restrict__ xc) {
    const int I = 3072, L = 2048, LD = 6144;
    int idx = blockIdx.x * 256 + threadIdx.x;    // over BL*I/8
    int i8 = (idx % (I / 8)) * 8;
    int bl = idx / (I / 8);
    int l = bl & (L - 1);
    float s[8];
    {
        float4 b0 = *reinterpret_cast<const float4*>(cb + i8);
        float4 b1 = *reinterpret_cast<const float4*>(cb + i8 + 4);
        s[0]=b0.x; s[1]=b0.y; s[2]=b0.z; s[3]=b0.w; s[4]=b1.x; s[5]=b1.y; s[6]=b1.z; s[7]=b1.w;
    }
    float w[8][4];
#pragma unroll
    for (int c = 0; c < 8; c++) {
        float4 wr = *reinterpret_cast<const float4*>(cw + (i8 + c) * 4);
        w[c][0]=wr.x; w[c][1]=wr.y; w[c][2]=wr.z; w[c][3]=wr.w;
    }
#pragma unroll
    for (int j = 0; j < 4; j++) {
        if (l + j - 3 >= 0) {
            uint4 r = *reinterpret_cast<const uint4*>(projbf + (size_t)(bl + j - 3) * LD + i8);
            float xv[8];
            xv[0]=b2f((unsigned short)(r.x & 0xffff)); xv[1]=b2f((unsigned short)(r.x >> 16));
            xv[2]=b2f((unsigned short)(r.y & 0xffff)); xv[3]=b2f((unsigned short)(r.y >> 16));
            xv[4]=b2f((unsigned short)(r.z & 0xffff)); xv[5]=b2f((unsigned short)(r.z >> 16));
            xv[6]=b2f((unsigned short)(r.w & 0xffff)); xv[7]=b2f((unsigned short)(r.w >> 16));
#pragma unroll
            for (int c = 0; c < 8; c++) s[c] = fmaf(xv[c], w[c][j], s[c]);
        }
    }
    unsigned short o[8];
#pragma unroll
    for (int c = 0; c < 8; c++) o[c] = f2b(silu_f(s[c]));
    uint4 packed;
    packed.x = (unsigned)o[0] | ((unsigned)o[1] << 16);
    packed.y = (unsigned)o[2] | ((unsigned)o[3] << 16);
    packed.z = (unsigned)o[4] | ((unsigned)o[5] << 16);
    packed.w = (unsigned)o[6] | ((unsigned)o[7] << 16);
    *reinterpret_cast<uint4*>(xc + (size_t)bl * I + i8) = packed;
}

// ---------- pass A: per-chunk local scan, 2 channels/thread ----------
// thread handles channels i and i+1536; bc[t] LDS broadcast amortized 2x;
// stages only the B half (cols 96..111) since C is unused here.
__global__ __launch_bounds__(256)
void scan_passA(const unsigned short* __restrict__ delta_bf, const unsigned short* __restrict__ xc,
                const float* __restrict__ ssmp, const float* __restrict__ Aw,
                float* __restrict__ S_local, float* __restrict__ sumDelta) {
    const int I = 3072, L = 2048, HI = 1536;
    __shared__ float bc[TCH][16];
    int g = blockIdx.x * 256 + threadIdx.x;      // over Bsz*CCH*HI
    int i = g % HI;
    int bcid = g / HI;
    int c = bcid % CCH;
    int b = bcid / CCH;
    size_t rowbase = (size_t)b * L + (size_t)c * TCH;
    {
        int e = threadIdx.x;                     // TCH*4 = 256 exactly
        int t = e >> 2, q = e & 3;
        float4 v = *reinterpret_cast<const float4*>(ssmp + (rowbase + t) * 128 + 96 + q * 4);
        *reinterpret_cast<float4*>(&bc[t][q * 4]) = v;
    }
    __syncthreads();

    float A0[16], A1[16], s0[16], s1[16];
#pragma unroll
    for (int n = 0; n < 16; n++) {
        A0[n] = Aw[i * 16 + n];
        A1[n] = Aw[(i + HI) * 16 + n];
        s0[n] = 0.f; s1[n] = 0.f;
    }
    float sum0 = 0.f, sum1 = 0.f;

    size_t rowI = rowbase * I + i;
    for (int t = 0; t < TCH; t++) {
        float d0 = b2f(delta_bf[rowI]);
        float d1 = b2f(delta_bf[rowI + HI]);
        float du0 = d0 * b2f(xc[rowI]);
        float du1 = d1 * b2f(xc[rowI + HI]);
        sum0 += d0; sum1 += d1;
        float4 b0 = *reinterpret_cast<const float4*>(&bc[t][0]);
        float4 b1v = *reinterpret_cast<const float4*>(&bc[t][4]);
        float4 b2 = *reinterpret_cast<const float4*>(&bc[t][8]);
        float4 b3 = *reinterpret_cast<const float4*>(&bc[t][12]);
        const float bv[16] = {b0.x,b0.y,b0.z,b0.w, b1v.x,b1v.y,b1v.z,b1v.w,
                              b2.x,b2.y,b2.z,b2.w, b3.x,b3.y,b3.z,b3.w};
#pragma unroll
        for (int n = 0; n < 16; n++) {
            s0[n] = fmaf(s0[n], __expf(d0 * A0[n]), du0 * bv[n]);
            s1[n] = fmaf(s1[n], __expf(d1 * A1[n]), du1 * bv[n]);
        }
        rowI += I;
    }
    size_t obase = (size_t)bcid * 16 * I + i;
#pragma unroll
    for (int n = 0; n < 16; n++) {
        S_local[obase + (size_t)n * I]      = s0[n];
        S_local[obase + (size_t)n * I + HI] = s1[n];
    }
    sumDelta[(size_t)bcid * I + i]      = sum0;
    sumDelta[(size_t)bcid * I + i + HI] = sum1;
}

// ---------- pass B: sequential combine across chunks -> state_in ----------
__global__ __launch_bounds__(256)
void scan_passB(const float* __restrict__ S_local, const float* __restrict__ sumDelta,
                const float* __restrict__ Aw, float* __restrict__ state_in) {
    const int I = 3072;
    int g = blockIdx.x * 256 + threadIdx.x;
    int i = g % I;
    int bn = g / I;
    int n = bn & 15;
    int b = bn >> 4;
    float a = Aw[i * 16 + n];
    float state = 0.f;
    for (int c = 0; c < CCH; c++) {
        int bcid = b * CCH + c;
        size_t idx = ((size_t)bcid * 16 + n) * I + i;
        state_in[idx] = state;
        state = fmaf(state, __expf(a * sumDelta[(size_t)bcid * I + i]), S_local[idx]);
    }
}

// ---------- pass C: re-scan from state_in, 2 channels/thread ----------
__global__ __launch_bounds__(256)
void scan_passC(const unsigned short* __restrict__ projbf,   // silu(gate) at col 3072+i, ld 6144
                const unsigned short* __restrict__ xc,
                const float* __restrict__ ssmp, const unsigned short* __restrict__ delta_bf,
                const float* __restrict__ Aw, const float* __restrict__ Dw,
                const float* __restrict__ state_in, unsigned short* __restrict__ ybf) {
    const int I = 3072, L = 2048, LD = 6144, HI = 1536;
    __shared__ float bc[TCH][32];
    int g = blockIdx.x * 256 + threadIdx.x;      // over Bsz*CCH*HI
    int i = g % HI;
    int bcid = g / HI;
    int c = bcid % CCH;
    int b = bcid / CCH;
    size_t rowbase = (size_t)b * L + (size_t)c * TCH;
    for (int e = threadIdx.x; e < TCH * 8; e += 256) {
        int t = e >> 3, q = e & 7;
        float4 v = *reinterpret_cast<const float4*>(ssmp + (rowbase + t) * 128 + 96 + q * 4);
        *reinterpret_cast<float4*>(&bc[t][q * 4]) = v;
    }
    __syncthreads();

    float A0[16], A1[16], s0[16], s1[16];
#pragma unroll
    for (int n = 0; n < 16; n++) {
        A0[n] = Aw[i * 16 + n];
        A1[n] = Aw[(i + HI) * 16 + n];
    }
    float D0 = Dw[i], D1 = Dw[i + HI];
    size_t sbase = (size_t)bcid * 16 * I + i;
#pragma unroll
    for (int n = 0; n < 16; n++) {
        s0[n] = state_in[sbase + (size_t)n * I];
        s1[n] = state_in[sbase + (size_t)n * I + HI];
    }

    size_t rowI = rowbase * I + i;
    size_t rowG = rowbase * LD + I + i;
    for (int t = 0; t < TCH; t++) {
        float d0 = b2f(delta_bf[rowI]);
        float d1 = b2f(delta_bf[rowI + HI]);
        float u0 = b2f(xc[rowI]);
        float u1 = b2f(xc[rowI + HI]);
        float du0 = d0 * u0, du1 = d1 * u1;
        float4 v0 = *reinterpret_cast<const float4*>(&bc[t][0]);
        float4 v1 = *reinterpret_cast<const float4*>(&bc[t][4]);
        float4 v2 = *reinterpret_cast<const float4*>(&bc[t][8]);
        float4 v3 = *reinterpret_cast<const float4*>(&bc[t][12]);
        float4 w0 = *reinterpret_cast<const float4*>(&bc[t][16]);
        float4 w1 = *reinterpret_cast<const float4*>(&bc[t][20]);
        float4 w2 = *reinterpret_cast<const float4*>(&bc[t][24]);
        float4 w3 = *reinterpret_cast<const float4*>(&bc[t][28]);
        const float bv[16] = {v0.x,v0.y,v0.z,v0.w, v1.x,v1.y,v1.z,v1.w,
                              v2.x,v2.y,v2.z,v2.w, v3.x,v3.y,v3.z,v3.w};
        const float cv[16] = {w0.x,w0.y,w0.z,w0.w, w1.x,w1.y,w1.z,w1.w,
                              w2.x,w2.y,w2.z,w2.w, w3.x,w3.y,w3.z,w3.w};
        float y0 = 0.f, y1 = 0.f;
#pragma unroll
        for (int n = 0; n < 16; n++) {
            s0[n] = fmaf(s0[n], __expf(d0 * A0[n]), du0 * bv[n]);
            s1[n] = fmaf(s1[n], __expf(d1 * A1[n]), du1 * bv[n]);
            y0 = fmaf(s0[n], cv[n], y0);
            y1 = fmaf(s1[n], cv[n], y1);
        }
        y0 = fmaf(u0, D0, y0);
        y1 = fmaf(u1, D1, y1);
        y0 *= b2f(projbf[rowG]);
        y1 *= b2f(projbf[rowG + HI]);
        ybf[rowI]      = f2b(y0);
        ybf[rowI + HI] = f2b(y1);
        rowI += I;
        rowG += LD;
    }
}

extern "C" void kernel_launch(void* const* d_in, const int* in_sizes, int n_in,
                              void* d_out, int out_size, void* d_ws, size_t ws_size,
                              hipStream_t stream) {
    const float* hidden  = (const float*)d_in[0];
    const float* W_in    = (const float*)d_in[1];
    const float* conv_w  = (const float*)d_in[2];
    const float* conv_b  = (const float*)d_in[3];
    const float* W_x     = (const float*)d_in[4];
    const float* W_dt    = (const float*)d_in[5];
    const float* dt_bias = (const float*)d_in[6];
    const float* Aw      = (const float*)d_in[7];
    const float* Dw      = (const float*)d_in[8];
    const float* W_out   = (const float*)d_in[9];
    float* out = (float*)d_out;

    constexpr int Bsz = 2, L = 2048, H = 1536, I = 3072, R = 96;
    constexpr int BL = Bsz * L;        // 4096
    constexpr int TwoI = 2 * I;        // 6144

    // ---- workspace layout ----
    char* base = (char*)d_ws;
    unsigned short* proj_bf  = (unsigned short*)base; base += (size_t)BL * TwoI * 2;   // 50.3 MB
    unsigned short* delta_bf = (unsigned short*)base; base += (size_t)BL * I * 2;      // 25.2 MB
    unsigned short* xc_bf    = (unsigned short*)base; base += (size_t)BL * I * 2;      // 25.2 MB
    unsigned short* y_bf     = (unsigned short*)base; base += (size_t)BL * I * 2;      // 25.2 MB
    float* ssmp              = (float*)base;          base += (size_t)BL * 128 * 4;    // 2.1 MB
    float* xpart             = (float*)base;          base += (size_t)8 * BL * 128 * 4;// 16.8 MB
    unsigned short* dtin_bf  = (unsigned short*)base; base += (size_t)BL * R * 2;      // 0.8 MB
    unsigned short* wx_bf    = (unsigned short*)base; base += (size_t)128 * I * 2;     // 0.8 MB
    unsigned short* wdt_bf   = (unsigned short*)base; base += (size_t)I * R * 2;       // 0.6 MB
    unsigned short* wout_bf  = (unsigned short*)base; base += (size_t)H * I * 2;       // 9.4 MB
    unsigned short* h_bf     = (unsigned short*)base; base += (size_t)BL * H * 2;      // 12.6 MB
    unsigned short* win_bf   = (unsigned short*)base; base += (size_t)TwoI * H * 2;    // 18.9 MB
    // scan scratch overlays h_bf+win_bf (dead after in_proj): 26.0 <= 31.5 MB
    float* S_local  = (float*)h_bf;
    float* sumDelta = S_local + (size_t)Bsz * CCH * 16 * I;
    float* state_in = sumDelta + (size_t)Bsz * CCH * I;

    dim3 blk(256);

    // 0) fused weight/act casts
    cast_all<<<(5283840 + 255) / 256, blk, 0, stream>>>(
        hidden, W_in, W_x, W_dt, W_out, h_bf, win_bf, wx_bf, wdt_bf, wout_bf);

    // 1) in_proj -> proj_bf [4096,6144] bf16; silu on gate half (cols >= 3072)
    //    256x384 tiles, grid EXACTLY 256 (one round)
    gemm_in<<<dim3(256, 1, 1), dim3(512), 0, stream>>>(
        h_bf, win_bf, proj_bf, H, H, H, TwoI, /*silu*/ I);

    // 2) causal conv + SiLU -> xc_bf
    conv_silu8<<<BL * I / 8 / 256, blk, 0, stream>>>(proj_bf, conv_w, conv_b, xc_bf);

    // 3) x_proj split-K x8: xpart[z][4096][128] = xc @ wx^T (K chunk 384)
    gemm_mfma<0><<<dim3(1, BL / 128, 8), blk, 0, stream>>>(
        xc_bf, wx_bf, xpart, I / 8, I, I, 128, nullptr, 0, (long long)BL * 128);
    reduce_xpart<<<BL * 32 / 256, blk, 0, stream>>>(xpart, ssmp, dtin_bf);

    // 4) dt_proj, fused +bias & softplus -> delta_bf [4096,3072] bf16
    gemm_mfma<3><<<dim3(I / 128, BL / 128, 1), blk, 0, stream>>>(
        dtin_bf, wdt_bf, delta_bf, R, R, R, I, dt_bias, 0, 0);

    // 5) chunk-parallel selective scan (passA/C: 2 channels per thread)
    scan_passA<<<Bsz * CCH * (I / 2) / 256, blk, 0, stream>>>(
        delta_bf, xc_bf, ssmp, Aw, S_local, sumDelta);
    scan_passB<<<Bsz * 16 * I / 256, blk, 0, stream>>>(
        S_local, sumDelta, Aw, state_in);
    scan_passC<<<Bsz * CCH * (I / 2) / 256, blk, 0, stream>>>(
        proj_bf, xc_bf, ssmp, delta_bf, Aw, Dw, state_in, y_bf);

    // 6) out_proj: 128x192 tiles, grid EXACTLY 256 blocks, fp32 direct to out
    gemm_out<<<dim3(256, 1, 1), dim3(512), 0, stream>>>(
        y_bf, wout_bf, out, I, I, I, H);
}

// Round 8
// 451.897 us; speedup vs baseline: 1.0594x; 1.0594x over previous
//
#include <hip/hip_runtime.h>

typedef __attribute__((ext_vector_type(8))) short bf16x8;
typedef __attribute__((ext_vector_type(4))) float f32x4;

#define CCH 32   // chunks over L
#define TCH 64   // chunk length

// ---------- bf16 helpers (round-to-nearest-even) ----------
__device__ __forceinline__ unsigned short f2b(float f) {
    unsigned u = __float_as_uint(f);
    return (unsigned short)((u + 0x7fffu + ((u >> 16) & 1u)) >> 16);
}
__device__ __forceinline__ float b2f(unsigned short h) {
    return __uint_as_float(((unsigned)h) << 16);
}
__device__ __forceinline__ float softplus_f(float z) {
    return (z > 15.f) ? z : __logf(1.f + __expf(z));
}
__device__ __forceinline__ float silu_f(float g) {
    return g / (1.f + __expf(-g));
}

// async 16B/lane global->LDS (lds dst = wave-uniform base + lane*16)
__device__ __forceinline__ void gload16(const unsigned short* g, unsigned short* l) {
    __builtin_amdgcn_global_load_lds(
        (const __attribute__((address_space(1))) void*)g,
        (__attribute__((address_space(3))) void*)l, 16, 0, 0);
}

// ---------- fused fp32 -> bf16 cast for all 5 tensors ----------
__global__ __launch_bounds__(256)
void cast_all(const float* __restrict__ h, const float* __restrict__ win,
              const float* __restrict__ wx, const float* __restrict__ wdt,
              const float* __restrict__ wout,
              unsigned short* __restrict__ dh, unsigned short* __restrict__ dwin,
              unsigned short* __restrict__ dwx, unsigned short* __restrict__ dwdt,
              unsigned short* __restrict__ dwout) {
    const int n0 = 1572864, n1 = n0 + 2359296, n2 = n1 + 98304,
              n3 = n2 + 73728, n4 = n3 + 1179648;
    int i = blockIdx.x * 256 + threadIdx.x;
    const float* s; unsigned short* d; int off;
    if (i < n0)      { s = h;    d = dh;    off = i; }
    else if (i < n1) { s = win;  d = dwin;  off = i - n0; }
    else if (i < n2) { s = wx;   d = dwx;   off = i - n1; }
    else if (i < n3) { s = wdt;  d = dwdt;  off = i - n2; }
    else if (i < n4) { s = wout; d = dwout; off = i - n3; }
    else return;
    float4 v = reinterpret_cast<const float4*>(s)[off];
    ushort4 o;
    o.x = f2b(v.x); o.y = f2b(v.y); o.z = f2b(v.z); o.w = f2b(v.w);
    reinterpret_cast<ushort4*>(d)[off] = o;
}

// ============================================================================
// in_proj GEMM: 256M x 384N tile, grid EXACTLY 256 blocks (one round), BK=32,
// K=1536 = 48 K-tiles, bf16 out with silu on cols >= silu_col0.
// 512 thr = 8 waves (2M x 4N): per-wave C = 128x96 = 8x6 frags.
// Swizzle (fixed vs r7): read slot = quad ^ ((row>>1)&3) -> bank
// b(row) = 16*(row&1) + 4*slot sweeps all 8 slots over 16 rows = exactly
// 2-way bank alias (free, m136).  Global source pre-swizzled to match:
// csw = ((lane&3) ^ ((lane>>3)&3))*8  (r16>>1 == lane>>3; all row-block
// offsets wr*128/wc*96/ni*16/mi*16 are even*8 so row-XOR term == (lr>>1)&3).
// ============================================================================
__global__ __launch_bounds__(512, 2)
void gemm_in(const unsigned short* __restrict__ A, const unsigned short* __restrict__ W,
             unsigned short* __restrict__ Cout, int Kc, int lda, int ldw, int ldc,
             int silu_col0) {
    __shared__ __align__(16) unsigned short A0s[8192];    // [256][32] bf16
    __shared__ __align__(16) unsigned short B0s[12288];   // [384][32] bf16
    __shared__ __align__(16) unsigned short A1s[8192];
    __shared__ __align__(16) unsigned short B1s[12288];
    const int tid  = threadIdx.x;
    const int lane = tid & 63;
    const int wave = tid >> 6;
    const int wr   = wave >> 2;    // 0..1 (128-row half)
    const int wc   = wave & 3;     // 0..3 (96-col group)
    const int lr   = lane & 15;
    const int quad = lane >> 4;    // frag k-slot (0..3)
    const int sw2  = (lr >> 1) & 3;   // read XOR (2-way-free bank spread)

    // 256 blocks: c = XCD, owns col-tiles c*2 and c*2+1
    const int c  = blockIdx.x & 7;
    const int j  = blockIdx.x >> 3;          // 0..31
    const int bn = (c * 2 + (j & 1)) * 384;
    const int bm = (j >> 1) * 256;

    // staging: 4 lanes/row (16B), 16 rows/wave/op; global col pre-swizzled
    const int rsub = wave * 16 + (lane >> 2);
    const int csw  = ((lane & 3) ^ ((lane >> 3) & 3)) * 8;
    const unsigned short* gA = A + (size_t)(bm + rsub) * lda + csw;
    const unsigned short* gB = W + (size_t)(bn + rsub) * ldw + csw;

#define STAGE_A(ARR, kt) do { \
        gload16(gA + (size_t)0   * lda + (kt) * 32, ARR + wave * 512); \
        gload16(gA + (size_t)128 * lda + (kt) * 32, ARR + 4096 + wave * 512); \
    } while (0)
#define STAGE_B(ARR, kt) do { \
        gload16(gB + (size_t)0   * ldw + (kt) * 32, ARR + wave * 512); \
        gload16(gB + (size_t)128 * ldw + (kt) * 32, ARR + 4096 + wave * 512); \
        gload16(gB + (size_t)256 * ldw + (kt) * 32, ARR + 8192 + wave * 512); \
    } while (0)

    // frag reads: row*32 elems + (quad ^ ((row>>1)&3))*8; (row>>1)&3 == sw2
#define LDA_F(ARR, mi) \
    (*reinterpret_cast<const bf16x8*>(&ARR[(wr * 128 + (mi) * 16 + lr) * 32 + ((quad ^ sw2)) * 8]))
#define LDB_F(ARR, ni) \
    (*reinterpret_cast<const bf16x8*>(&ARR[(wc * 96 + (ni) * 16 + lr) * 32 + ((quad ^ sw2)) * 8]))

#define PRIO1 __builtin_amdgcn_s_setprio(1)
#define PRIO0 __builtin_amdgcn_s_setprio(0)
#define VM0B  asm volatile("s_waitcnt vmcnt(0)\n\ts_barrier" ::: "memory")

    // body: fb[6] once, then 4 fa-pairs, 12 MFMA each (acc liveness capped)
#define TILE_BODY(AX, BX) do { \
        _Pragma("unroll") for (int ni = 0; ni < 6; ++ni) fb[ni] = LDB_F(BX, ni); \
        _Pragma("unroll") for (int mp = 0; mp < 4; ++mp) { \
            bf16x8 fa0 = LDA_F(AX, 2 * mp); \
            bf16x8 fa1 = LDA_F(AX, 2 * mp + 1); \
            PRIO1; \
            _Pragma("unroll") for (int ni = 0; ni < 6; ++ni) { \
                acc[2 * mp][ni]     = __builtin_amdgcn_mfma_f32_16x16x32_bf16(fa0, fb[ni], acc[2 * mp][ni], 0, 0, 0); \
                acc[2 * mp + 1][ni] = __builtin_amdgcn_mfma_f32_16x16x32_bf16(fa1, fb[ni], acc[2 * mp + 1][ni], 0, 0, 0); } \
            PRIO0; } \
    } while (0)

    f32x4 acc[8][6];
    const f32x4 zero = {0.f, 0.f, 0.f, 0.f};
#pragma unroll
    for (int m = 0; m < 8; ++m)
#pragma unroll
        for (int n = 0; n < 6; ++n) acc[m][n] = zero;

    bf16x8 fb[6];

    const int nkt = Kc >> 5;   // 48 (even)

    STAGE_A(A0s, 0); STAGE_B(B0s, 0);
    VM0B;

#pragma unroll 1
    for (int t = 0; t < nkt; t += 2) {
        if (t + 1 < nkt) { STAGE_A(A1s, t + 1); STAGE_B(B1s, t + 1); }
        TILE_BODY(A0s, B0s);
        VM0B;
        if (t + 1 < nkt) {
            if (t + 2 < nkt) { STAGE_A(A0s, t + 2); STAGE_B(B0s, t + 2); }
            TILE_BODY(A1s, B1s);
            VM0B;
        }
    }

    // C-write: row = bm + wr*128 + mi*16 + quad*4 + reg; col = bn + wc*96 + ni*16 + lr
#pragma unroll
    for (int mi = 0; mi < 8; ++mi) {
        const int row0 = bm + wr * 128 + mi * 16 + quad * 4;
#pragma unroll
        for (int ni = 0; ni < 6; ++ni) {
            const int col = bn + wc * 96 + ni * 16 + lr;
#pragma unroll
            for (int reg = 0; reg < 4; ++reg) {
                float v = acc[mi][ni][reg];
                if (col >= silu_col0) v = silu_f(v);
                Cout[(size_t)(row0 + reg) * ldc + col] = f2b(v);
            }
        }
    }
#undef STAGE_A
#undef STAGE_B
#undef LDA_F
#undef LDB_F
#undef PRIO1
#undef PRIO0
#undef VM0B
#undef TILE_BODY
}

// ============================================================================
// out_proj GEMM: 128M x 192N tile, grid EXACTLY 256 blocks, K=3072 single
// pass, fp32 direct to d_out (r6 version, measured best).
// ============================================================================
__global__ __launch_bounds__(512)
void gemm_out(const unsigned short* __restrict__ A, const unsigned short* __restrict__ W,
              float* __restrict__ Cout, int Kc, int lda, int ldw, int ldc) {
    __shared__ __align__(16) unsigned short A0s[8192];    // 128x64 bf16
    __shared__ __align__(16) unsigned short B0s[12288];   // 192x64 bf16
    __shared__ __align__(16) unsigned short A1s[8192];
    __shared__ __align__(16) unsigned short B1s[12288];
    const int tid  = threadIdx.x;
    const int lane = tid & 63;
    const int wave = tid >> 6;
    const int wr   = wave >> 2;    // 0..1 (64-row half)
    const int wc   = wave & 3;     // 0..3 (48-col group)
    const int lr   = lane & 15;
    const int quad = lane >> 4;
    const int sw   = lr & 7;

    // grid 256 = 8 XCD col-stripes x 32 M-tiles
    const int c  = blockIdx.x & 7;
    const int j  = blockIdx.x >> 3;   // 0..31
    const int bm = j * 128;
    const int bn = c * 192;

    const int rsub = wave * 8 + (lane >> 3);
    const int csw  = ((lane & 7) ^ ((lane >> 3) & 7)) * 8;
    const unsigned short* gA = A + (size_t)(bm + rsub) * lda + csw;
    const unsigned short* gB = W + (size_t)(bn + rsub) * ldw + csw;

#define STAGE_A(ARR, kt) do { \
        gload16(gA + (size_t)0  * lda + (kt) * 64, ARR + 0    + wave * 512); \
        gload16(gA + (size_t)64 * lda + (kt) * 64, ARR + 4096 + wave * 512); \
    } while (0)
#define STAGE_B(ARR, kt) do { \
        gload16(gB + (size_t)0   * ldw + (kt) * 64, ARR + 0    + wave * 512); \
        gload16(gB + (size_t)64  * ldw + (kt) * 64, ARR + 4096 + wave * 512); \
        gload16(gB + (size_t)128 * ldw + (kt) * 64, ARR + 8192 + wave * 512); \
    } while (0)

#define LDA_F(ARR, mi, kk) \
    (*reinterpret_cast<const bf16x8*>(&ARR[(wr * 64 + (mi) * 16 + lr) * 64 + (((((kk) << 2) | quad)) ^ sw) * 8]))
#define LDB_F(ARR, ni, kk) \
    (*reinterpret_cast<const bf16x8*>(&ARR[(wc * 48 + (ni) * 16 + lr) * 64 + (((((kk) << 2) | quad)) ^ sw) * 8]))

#define PRIO1 __builtin_amdgcn_s_setprio(1)
#define PRIO0 __builtin_amdgcn_s_setprio(0)
#define VM0B  asm volatile("s_waitcnt vmcnt(0)\n\ts_barrier" ::: "memory")

#define TILE_BODY(AX, BX) do { \
        _Pragma("unroll") for (int ni = 0; ni < 3; ++ni) { \
            fb[ni][0] = LDB_F(BX, ni, 0); fb[ni][1] = LDB_F(BX, ni, 1); } \
        _Pragma("unroll") for (int mi = 0; mi < 4; ++mi) { \
            fa[mi][0] = LDA_F(AX, mi, 0); fa[mi][1] = LDA_F(AX, mi, 1); } \
        PRIO1; \
        _Pragma("unroll") for (int mi = 0; mi < 4; ++mi) \
        _Pragma("unroll") for (int ni = 0; ni < 3; ++ni) { \
            acc[mi][ni] = __builtin_amdgcn_mfma_f32_16x16x32_bf16(fa[mi][0], fb[ni][0], acc[mi][ni], 0, 0, 0); \
            acc[mi][ni] = __builtin_amdgcn_mfma_f32_16x16x32_bf16(fa[mi][1], fb[ni][1], acc[mi][ni], 0, 0, 0); } \
        PRIO0; \
    } while (0)

    f32x4 acc[4][3];
    const f32x4 zero = {0.f, 0.f, 0.f, 0.f};
#pragma unroll
    for (int m = 0; m < 4; ++m)
#pragma unroll
        for (int n = 0; n < 3; ++n) acc[m][n] = zero;

    bf16x8 fa[4][2], fb[3][2];

    const int nkt = Kc >> 6;   // 48 (even)

    STAGE_A(A0s, 0); STAGE_B(B0s, 0);
    VM0B;

#pragma unroll 1
    for (int t = 0; t < nkt; t += 2) {
        if (t + 1 < nkt) { STAGE_A(A1s, t + 1); STAGE_B(B1s, t + 1); }
        TILE_BODY(A0s, B0s);
        VM0B;
        if (t + 1 < nkt) {
            if (t + 2 < nkt) { STAGE_A(A0s, t + 2); STAGE_B(B0s, t + 2); }
            TILE_BODY(A1s, B1s);
            VM0B;
        }
    }

#pragma unroll
    for (int mi = 0; mi < 4; ++mi) {
        const int row0 = bm + wr * 64 + mi * 16 + quad * 4;
#pragma unroll
        for (int ni = 0; ni < 3; ++ni) {
            const int col = bn + wc * 48 + ni * 16 + lr;
#pragma unroll
            for (int reg = 0; reg < 4; ++reg)
                Cout[(size_t)(row0 + reg) * ldc + col] = acc[mi][ni][reg];
        }
    }
#undef STAGE_A
#undef STAGE_B
#undef LDA_F
#undef LDB_F
#undef PRIO1
#undef PRIO0
#undef VM0B
#undef TILE_BODY
}

// ---------- MFMA GEMM, 3-stage pipelined async LDS staging (128x128) ----------
// kept for x_proj (N=128) and dt_proj (K=96).
// OP=0: fp32 store (+ split-K z, C offset kz*czs)
// OP=3: bf16 store of softplus(acc + bias[col])
template <int OP>
__global__ __launch_bounds__(256)
void gemm_mfma(const unsigned short* __restrict__ A, const unsigned short* __restrict__ W,
               void* __restrict__ Cout, int Kc, int lda, int ldw, int ldc,
               const float* __restrict__ bias, int silu_col0, long long czs) {
    __shared__ unsigned short As[3][4096];   // 3 x 128x32 bf16 = 24 KB
    __shared__ unsigned short Bs[3][4096];
    const int tid = threadIdx.x;
    const int bm = blockIdx.y * 128;
    const int bn = blockIdx.x * 128;
    const int kz = blockIdx.z;
    A += (size_t)kz * Kc;
    W += (size_t)kz * Kc;
    const int lane = tid & 63;
    const int wave = tid >> 6;
    const int r_a = lane >> 2;          // row within 16-row chunk
    const int k8 = (lane & 3) * 8;      // k offset (8 bf16 = 16B)

    const unsigned short* gA0 = A + (size_t)(bm + wave * 16 + r_a) * lda + k8;
    const unsigned short* gA1 = A + (size_t)(bm + 64 + wave * 16 + r_a) * lda + k8;
    const unsigned short* gB0 = W + (size_t)(bn + wave * 16 + r_a) * ldw + k8;
    const unsigned short* gB1 = W + (size_t)(bn + 64 + wave * 16 + r_a) * ldw + k8;

    const int wm = (wave & 1) * 64;
    const int wn = (wave >> 1) * 64;
    const int lr = lane & 15;
    const int quad = lane >> 4;

    f32x4 acc[4][4];
    const f32x4 zero = {0.f, 0.f, 0.f, 0.f};
#pragma unroll
    for (int i = 0; i < 4; i++)
#pragma unroll
        for (int j = 0; j < 4; j++) acc[i][j] = zero;

#define STAGE(koff, j) do { \
        gload16(gA0 + (koff), As[j] + wave * 512); \
        gload16(gA1 + (koff), As[j] + (wave + 4) * 512); \
        gload16(gB0 + (koff), Bs[j] + wave * 512); \
        gload16(gB1 + (koff), Bs[j] + (wave + 4) * 512); \
    } while (0)

    const int niter = Kc >> 5;
    STAGE(0, 0);
    if (niter > 1) STAGE(32, 1);

    int ib = 0;   // LDS buffer holding tile k
    for (int k = 0; k < niter; k++) {
        if (k + 1 < niter)
            asm volatile("s_waitcnt vmcnt(4)\n\ts_barrier" ::: "memory");
        else
            asm volatile("s_waitcnt vmcnt(0)\n\ts_barrier" ::: "memory");
        if (k + 2 < niter) {
            int is_ = ib + 2; if (is_ >= 3) is_ -= 3;
            STAGE((k + 2) << 5, is_);
        }
        const unsigned short* as = As[ib];
        const unsigned short* bs = Bs[ib];
        bf16x8 fa[4], fb[4];
#pragma unroll
        for (int mi = 0; mi < 4; mi++)
            fa[mi] = *reinterpret_cast<const bf16x8*>(as + (wm + mi * 16 + lr) * 32 + quad * 8);
#pragma unroll
        for (int ni = 0; ni < 4; ni++)
            fb[ni] = *reinterpret_cast<const bf16x8*>(bs + (wn + ni * 16 + lr) * 32 + quad * 8);
#pragma unroll
        for (int mi = 0; mi < 4; mi++)
#pragma unroll
            for (int ni = 0; ni < 4; ni++)
                acc[mi][ni] = __builtin_amdgcn_mfma_f32_16x16x32_bf16(fa[mi], fb[ni], acc[mi][ni], 0, 0, 0);
        ib = (ib == 2) ? 0 : ib + 1;
    }
#undef STAGE

    // C/D layout: col = lane&15 (+16*ni), row = quad*4 + reg (+16*mi)
#pragma unroll
    for (int mi = 0; mi < 4; mi++)
#pragma unroll
        for (int reg = 0; reg < 4; reg++) {
            int row = bm + wm + mi * 16 + quad * 4 + reg;
#pragma unroll
            for (int ni = 0; ni < 4; ni++) {
                int col = bn + wn + ni * 16 + lr;
                float v = acc[mi][ni][reg];
                if (OP == 0) {
                    float* Cf = (float*)Cout + (size_t)kz * czs;
                    Cf[(size_t)row * ldc + col] = v;
                } else if (OP == 2) {
                    if (col >= silu_col0) v = silu_f(v);
                    ((unsigned short*)Cout)[(size_t)row * ldc + col] = f2b(v);
                } else {  // OP == 3
                    ((unsigned short*)Cout)[(size_t)row * ldc + col] = f2b(softplus_f(v + bias[col]));
                }
            }
        }
}

// ---------- split-K reduction for x_proj; fuses dtin bf16 extraction ----------
__global__ __launch_bounds__(256)
void reduce_xpart(const float* __restrict__ xpart, float* __restrict__ ssmp,
                  unsigned short* __restrict__ dtin) {
    const int BL = 4096;
    int idx = blockIdx.x * 256 + threadIdx.x;   // BL*32 threads
    int row = idx >> 5;
    int c4 = (idx & 31) * 4;
    float4 s = {0.f, 0.f, 0.f, 0.f};
#pragma unroll
    for (int z = 0; z < 8; z++) {
        float4 v = *reinterpret_cast<const float4*>(xpart + (size_t)z * BL * 128 + (size_t)row * 128 + c4);
        s.x += v.x; s.y += v.y; s.z += v.z; s.w += v.w;
    }
    *reinterpret_cast<float4*>(ssmp + (size_t)row * 128 + c4) = s;
    if (c4 < 96) {
        ushort4 o;
        o.x = f2b(s.x); o.y = f2b(s.y); o.z = f2b(s.z); o.w = f2b(s.w);
        *reinterpret_cast<ushort4*>(dtin + (size_t)row * 96 + c4) = o;
    }
}

// ---------- causal depthwise conv (K=4) + SiLU, 8 channels/thread ----------
__global__ __launch_bounds__(256)
void conv_silu8(const unsigned short* __restrict__ projbf, const float* __restrict__ cw,
                const float* __restrict__ cb, unsigned short* __restrict__ xc) {
    const int I = 3072, L = 2048, LD = 6144;
    int idx = blockIdx.x * 256 + threadIdx.x;    // over BL*I/8
    int i8 = (idx % (I / 8)) * 8;
    int bl = idx / (I / 8);
    int l = bl & (L - 1);
    float s[8];
    {
        float4 b0 = *reinterpret_cast<const float4*>(cb + i8);
        float4 b1 = *reinterpret_cast<const float4*>(cb + i8 + 4);
        s[0]=b0.x; s[1]=b0.y; s[2]=b0.z; s[3]=b0.w; s[4]=b1.x; s[5]=b1.y; s[6]=b1.z; s[7]=b1.w;
    }
    float w[8][4];
#pragma unroll
    for (int c = 0; c < 8; c++) {
        float4 wr = *reinterpret_cast<const float4*>(cw + (i8 + c) * 4);
        w[c][0]=wr.x; w[c][1]=wr.y; w[c][2]=wr.z; w[c][3]=wr.w;
    }
#pragma unroll
    for (int j = 0; j < 4; j++) {
        if (l + j - 3 >= 0) {
            uint4 r = *reinterpret_cast<const uint4*>(projbf + (size_t)(bl + j - 3) * LD + i8);
            float xv[8];
            xv[0]=b2f((unsigned short)(r.x & 0xffff)); xv[1]=b2f((unsigned short)(r.x >> 16));
            xv[2]=b2f((unsigned short)(r.y & 0xffff)); xv[3]=b2f((unsigned short)(r.y >> 16));
            xv[4]=b2f((unsigned short)(r.z & 0xffff)); xv[5]=b2f((unsigned short)(r.z >> 16));
            xv[6]=b2f((unsigned short)(r.w & 0xffff)); xv[7]=b2f((unsigned short)(r.w >> 16));
#pragma unroll
            for (int c = 0; c < 8; c++) s[c] = fmaf(xv[c], w[c][j], s[c]);
        }
    }
    unsigned short o[8];
#pragma unroll
    for (int c = 0; c < 8; c++) o[c] = f2b(silu_f(s[c]));
    uint4 packed;
    packed.x = (unsigned)o[0] | ((unsigned)o[1] << 16);
    packed.y = (unsigned)o[2] | ((unsigned)o[3] << 16);
    packed.z = (unsigned)o[4] | ((unsigned)o[5] << 16);
    packed.w = (unsigned)o[6] | ((unsigned)o[7] << 16);
    *reinterpret_cast<uint4*>(xc + (size_t)bl * I + i8) = packed;
}

// ---------- pass A: per-chunk local scan (init 0) -> S_local, sumDelta ----------
__global__ __launch_bounds__(256)
void scan_passA(const unsigned short* __restrict__ delta_bf, const unsigned short* __restrict__ xc,
                const float* __restrict__ ssmp, const float* __restrict__ Aw,
                float* __restrict__ S_local, float* __restrict__ sumDelta) {
    const int I = 3072, L = 2048;
    __shared__ float bc[TCH][32];
    int g = blockIdx.x * 256 + threadIdx.x;
    int i = g % I;
    int bcid = g / I;
    int c = bcid % CCH;
    int b = bcid / CCH;
    size_t rowbase = (size_t)b * L + (size_t)c * TCH;
    for (int e = threadIdx.x; e < TCH * 8; e += 256) {
        int t = e >> 3, q = e & 7;
        float4 v = *reinterpret_cast<const float4*>(ssmp + (rowbase + t) * 128 + 96 + q * 4);
        *reinterpret_cast<float4*>(&bc[t][q * 4]) = v;
    }
    __syncthreads();

    float Arow[16];
#pragma unroll
    for (int n = 0; n < 16; n++) Arow[n] = Aw[i * 16 + n];
    float st[16];
#pragma unroll
    for (int n = 0; n < 16; n++) st[n] = 0.f;
    float sumD = 0.f;

    size_t rowI = rowbase * I + i;
    for (int t = 0; t < TCH; t++) {
        float delta = b2f(delta_bf[rowI]);
        float du = delta * b2f(xc[rowI]);
        sumD += delta;
        float4 b0 = *reinterpret_cast<const float4*>(&bc[t][0]);
        float4 b1 = *reinterpret_cast<const float4*>(&bc[t][4]);
        float4 b2 = *reinterpret_cast<const float4*>(&bc[t][8]);
        float4 b3 = *reinterpret_cast<const float4*>(&bc[t][12]);
        const float bv[16] = {b0.x,b0.y,b0.z,b0.w, b1.x,b1.y,b1.z,b1.w,
                              b2.x,b2.y,b2.z,b2.w, b3.x,b3.y,b3.z,b3.w};
#pragma unroll
        for (int n = 0; n < 16; n++)
            st[n] = fmaf(st[n], __expf(delta * Arow[n]), du * bv[n]);
        rowI += I;
    }
    size_t obase = (size_t)bcid * 16 * I + i;
#pragma unroll
    for (int n = 0; n < 16; n++) S_local[obase + (size_t)n * I] = st[n];
    sumDelta[(size_t)bcid * I + i] = sumD;
}

// ---------- pass B: sequential combine across chunks -> state_in ----------
__global__ __launch_bounds__(256)
void scan_passB(const float* __restrict__ S_local, const float* __restrict__ sumDelta,
                const float* __restrict__ Aw, float* __restrict__ state_in) {
    const int I = 3072;
    int g = blockIdx.x * 256 + threadIdx.x;
    int i = g % I;
    int bn = g / I;
    int n = bn & 15;
    int b = bn >> 4;
    float a = Aw[i * 16 + n];
    float state = 0.f;
    for (int c = 0; c < CCH; c++) {
        int bcid = b * CCH + c;
        size_t idx = ((size_t)bcid * 16 + n) * I + i;
        state_in[idx] = state;
        state = fmaf(state, __expf(a * sumDelta[(size_t)bcid * I + i]), S_local[idx]);
    }
}

// ---------- pass C: re-scan from state_in; fused y, D-skip, pre-silu'd gate ----------
__global__ __launch_bounds__(256)
void scan_passC(const unsigned short* __restrict__ projbf,   // silu(gate) at col 3072+i, ld 6144
                const unsigned short* __restrict__ xc,
                const float* __restrict__ ssmp, const unsigned short* __restrict__ delta_bf,
                const float* __restrict__ Aw, const float* __restrict__ Dw,
                const float* __restrict__ state_in, unsigned short* __restrict__ ybf) {
    const int I = 3072, L = 2048, LD = 6144;
    __shared__ float bc[TCH][32];
    int g = blockIdx.x * 256 + threadIdx.x;
    int i = g % I;
    int bcid = g / I;
    int c = bcid % CCH;
    int b = bcid / CCH;
    size_t rowbase = (size_t)b * L + (size_t)c * TCH;
    for (int e = threadIdx.x; e < TCH * 8; e += 256) {
        int t = e >> 3, q = e & 7;
        float4 v = *reinterpret_cast<const float4*>(ssmp + (rowbase + t) * 128 + 96 + q * 4);
        *reinterpret_cast<float4*>(&bc[t][q * 4]) = v;
    }
    __syncthreads();

    float Arow[16];
#pragma unroll
    for (int n = 0; n < 16; n++) Arow[n] = Aw[i * 16 + n];
    float Dv = Dw[i];
    float st[16];
    size_t sbase = (size_t)bcid * 16 * I + i;
#pragma unroll
    for (int n = 0; n < 16; n++) st[n] = state_in[sbase + (size_t)n * I];

    size_t rowI = rowbase * I + i;
    size_t rowG = rowbase * LD + I + i;
    for (int t = 0; t < TCH; t++) {
        float delta = b2f(delta_bf[rowI]);
        float u = b2f(xc[rowI]);
        float du = delta * u;
        float4 b0 = *reinterpret_cast<const float4*>(&bc[t][0]);
        float4 b1 = *reinterpret_cast<const float4*>(&bc[t][4]);
        float4 b2 = *reinterpret_cast<const float4*>(&bc[t][8]);
        float4 b3 = *reinterpret_cast<const float4*>(&bc[t][12]);
        float4 c0 = *reinterpret_cast<const float4*>(&bc[t][16]);
        float4 c1 = *reinterpret_cast<const float4*>(&bc[t][20]);
        float4 c2 = *reinterpret_cast<const float4*>(&bc[t][24]);
        float4 c3 = *reinterpret_cast<const float4*>(&bc[t][28]);
        const float bv[16] = {b0.x,b0.y,b0.z,b0.w, b1.x,b1.y,b1.z,b1.w,
                              b2.x,b2.y,b2.z,b2.w, b3.x,b3.y,b3.z,b3.w};
        const float cv[16] = {c0.x,c0.y,c0.z,c0.w, c1.x,c1.y,c1.z,c1.w,
                              c2.x,c2.y,c2.z,c2.w, c3.x,c3.y,c3.z,c3.w};
        float y = 0.f;
#pragma unroll
        for (int n = 0; n < 16; n++) {
            st[n] = fmaf(st[n], __expf(delta * Arow[n]), du * bv[n]);
            y = fmaf(st[n], cv[n], y);
        }
        y = fmaf(u, Dv, y);
        y *= b2f(projbf[rowG]);            // gate already silu'd in GEMM epilogue
        ybf[rowI] = f2b(y);
        rowI += I;
        rowG += LD;
    }
}

extern "C" void kernel_launch(void* const* d_in, const int* in_sizes, int n_in,
                              void* d_out, int out_size, void* d_ws, size_t ws_size,
                              hipStream_t stream) {
    const float* hidden  = (const float*)d_in[0];
    const float* W_in    = (const float*)d_in[1];
    const float* conv_w  = (const float*)d_in[2];
    const float* conv_b  = (const float*)d_in[3];
    const float* W_x     = (const float*)d_in[4];
    const float* W_dt    = (const float*)d_in[5];
    const float* dt_bias = (const float*)d_in[6];
    const float* Aw      = (const float*)d_in[7];
    const float* Dw      = (const float*)d_in[8];
    const float* W_out   = (const float*)d_in[9];
    float* out = (float*)d_out;

    constexpr int Bsz = 2, L = 2048, H = 1536, I = 3072, R = 96;
    constexpr int BL = Bsz * L;        // 4096
    constexpr int TwoI = 2 * I;        // 6144

    // ---- workspace layout ----
    char* base = (char*)d_ws;
    unsigned short* proj_bf  = (unsigned short*)base; base += (size_t)BL * TwoI * 2;   // 50.3 MB
    unsigned short* delta_bf = (unsigned short*)base; base += (size_t)BL * I * 2;      // 25.2 MB
    unsigned short* xc_bf    = (unsigned short*)base; base += (size_t)BL * I * 2;      // 25.2 MB
    unsigned short* y_bf     = (unsigned short*)base; base += (size_t)BL * I * 2;      // 25.2 MB
    float* ssmp              = (float*)base;          base += (size_t)BL * 128 * 4;    // 2.1 MB
    float* xpart             = (float*)base;          base += (size_t)8 * BL * 128 * 4;// 16.8 MB
    unsigned short* dtin_bf  = (unsigned short*)base; base += (size_t)BL * R * 2;      // 0.8 MB
    unsigned short* wx_bf    = (unsigned short*)base; base += (size_t)128 * I * 2;     // 0.8 MB
    unsigned short* wdt_bf   = (unsigned short*)base; base += (size_t)I * R * 2;       // 0.6 MB
    unsigned short* wout_bf  = (unsigned short*)base; base += (size_t)H * I * 2;       // 9.4 MB
    unsigned short* h_bf     = (unsigned short*)base; base += (size_t)BL * H * 2;      // 12.6 MB
    unsigned short* win_bf   = (unsigned short*)base; base += (size_t)TwoI * H * 2;    // 18.9 MB
    // scan scratch overlays h_bf+win_bf (dead after in_proj): 26.0 <= 31.5 MB
    float* S_local  = (float*)h_bf;
    float* sumDelta = S_local + (size_t)Bsz * CCH * 16 * I;
    float* state_in = sumDelta + (size_t)Bsz * CCH * I;

    dim3 blk(256);

    // 0) fused weight/act casts
    cast_all<<<(5283840 + 255) / 256, blk, 0, stream>>>(
        hidden, W_in, W_x, W_dt, W_out, h_bf, win_bf, wx_bf, wdt_bf, wout_bf);

    // 1) in_proj -> proj_bf [4096,6144] bf16; silu on gate half (cols >= 3072)
    //    256x384 tiles, grid EXACTLY 256 (one round), fixed 2-way-free swizzle
    gemm_in<<<dim3(256, 1, 1), dim3(512), 0, stream>>>(
        h_bf, win_bf, proj_bf, H, H, H, TwoI, /*silu*/ I);

    // 2) causal conv + SiLU -> xc_bf
    conv_silu8<<<BL * I / 8 / 256, blk, 0, stream>>>(proj_bf, conv_w, conv_b, xc_bf);

    // 3) x_proj split-K x8: xpart[z][4096][128] = xc @ wx^T (K chunk 384)
    gemm_mfma<0><<<dim3(1, BL / 128, 8), blk, 0, stream>>>(
        xc_bf, wx_bf, xpart, I / 8, I, I, 128, nullptr, 0, (long long)BL * 128);
    reduce_xpart<<<BL * 32 / 256, blk, 0, stream>>>(xpart, ssmp, dtin_bf);

    // 4) dt_proj, fused +bias & softplus -> delta_bf [4096,3072] bf16
    gemm_mfma<3><<<dim3(I / 128, BL / 128, 1), blk, 0, stream>>>(
        dtin_bf, wdt_bf, delta_bf, R, R, R, I, dt_bias, 0, 0);

    // 5) chunk-parallel selective scan (r6 1-channel/thread versions — the
    //    2-ch variant halved TLP on a latency-bound serial chain, +32 us)
    scan_passA<<<Bsz * I * CCH / 256, blk, 0, stream>>>(
        delta_bf, xc_bf, ssmp, Aw, S_local, sumDelta);
    scan_passB<<<Bsz * 16 * I / 256, blk, 0, stream>>>(
        S_local, sumDelta, Aw, state_in);
    scan_passC<<<Bsz * I * CCH / 256, blk, 0, stream>>>(
        proj_bf, xc_bf, ssmp, delta_bf, Aw, Dw, state_in, y_bf);

    // 6) out_proj: 128x192 tiles, grid EXACTLY 256 blocks, fp32 direct to out
    gemm_out<<<dim3(256, 1, 1), dim3(512), 0, stream>>>(
        y_bf, wout_bf, out, I, I, I, H);
}

// Round 9
// 450.122 us; speedup vs baseline: 1.0636x; 1.0039x over previous
//
#include <hip/hip_runtime.h>

typedef __attribute__((ext_vector_type(8))) short bf16x8;
typedef __attribute__((ext_vector_type(4))) float f32x4;

#define CCH 32   // chunks over L
#define TCH 64   // chunk length

// ---------- bf16 helpers (round-to-nearest-even) ----------
__device__ __forceinline__ unsigned short f2b(float f) {
    unsigned u = __float_as_uint(f);
    return (unsigned short)((u + 0x7fffu + ((u >> 16) & 1u)) >> 16);
}
__device__ __forceinline__ float b2f(unsigned short h) {
    return __uint_as_float(((unsigned)h) << 16);
}
__device__ __forceinline__ float softplus_f(float z) {
    return (z > 15.f) ? z : __logf(1.f + __expf(z));
}
__device__ __forceinline__ float silu_f(float g) {
    return g / (1.f + __expf(-g));
}

// async 16B/lane global->LDS (lds dst = wave-uniform base + lane*16)
__device__ __forceinline__ void gload16(const unsigned short* g, unsigned short* l) {
    __builtin_amdgcn_global_load_lds(
        (const __attribute__((address_space(1))) void*)g,
        (__attribute__((address_space(3))) void*)l, 16, 0, 0);
}

// ---------- fused fp32 -> bf16 cast for all 5 tensors ----------
__global__ __launch_bounds__(256)
void cast_all(const float* __restrict__ h, const float* __restrict__ win,
              const float* __restrict__ wx, const float* __restrict__ wdt,
              const float* __restrict__ wout,
              unsigned short* __restrict__ dh, unsigned short* __restrict__ dwin,
              unsigned short* __restrict__ dwx, unsigned short* __restrict__ dwdt,
              unsigned short* __restrict__ dwout) {
    const int n0 = 1572864, n1 = n0 + 2359296, n2 = n1 + 98304,
              n3 = n2 + 73728, n4 = n3 + 1179648;
    int i = blockIdx.x * 256 + threadIdx.x;
    const float* s; unsigned short* d; int off;
    if (i < n0)      { s = h;    d = dh;    off = i; }
    else if (i < n1) { s = win;  d = dwin;  off = i - n0; }
    else if (i < n2) { s = wx;   d = dwx;   off = i - n1; }
    else if (i < n3) { s = wdt;  d = dwdt;  off = i - n2; }
    else if (i < n4) { s = wout; d = dwout; off = i - n3; }
    else return;
    float4 v = reinterpret_cast<const float4*>(s)[off];
    ushort4 o;
    o.x = f2b(v.x); o.y = f2b(v.y); o.z = f2b(v.z); o.w = f2b(v.w);
    reinterpret_cast<ushort4*>(d)[off] = o;
}

// ============================================================================
// in_proj GEMM v3: 256M x 384N tile, BK=32, grid 256 (one round), but now
// 768 thr = 12 waves (2M x 6N, wave tile 128x64) -> 3 waves/SIMD (was 2).
// r8 counters showed MfmaUtil 36% + VALUBusy 23% + Occupancy 21% = latency
// bound at 2 waves/SIMD; +50% resident waves is the direct fix.
// acc[8][4]=128 VGPR + fb[4]=16 + fa pair=8 + addr ~= 165 <= 170 budget at
// __launch_bounds__(768,3).  LDS 80KB dbuf unchanged; swizzle unchanged
// (row-XOR term (row>>1)&3: all row-block offsets are == 0 mod 4 after >>1).
// Staging lines at 12 waves: A = 192-row line + 64-row remainder (waves 0-3),
// B = 2 x 192-row lines; per-lane LDS dst identity re-verified.
// ============================================================================
__global__ __launch_bounds__(768, 3)
void gemm_in(const unsigned short* __restrict__ A, const unsigned short* __restrict__ W,
             unsigned short* __restrict__ Cout, int Kc, int lda, int ldw, int ldc,
             int silu_col0) {
    __shared__ __align__(16) unsigned short A0s[8192];    // [256][32] bf16
    __shared__ __align__(16) unsigned short B0s[12288];   // [384][32] bf16
    __shared__ __align__(16) unsigned short A1s[8192];
    __shared__ __align__(16) unsigned short B1s[12288];
    const int tid  = threadIdx.x;
    const int lane = tid & 63;
    const int wave = tid >> 6;     // 0..11
    const int wr   = wave / 6;     // 0..1 (128-row half)
    const int wcc  = wave % 6;     // 0..5 (64-col group)
    const int lr   = lane & 15;
    const int quad = lane >> 4;    // frag k-slot (0..3)
    const int sw2  = (lr >> 1) & 3;   // read XOR (2-way-free bank spread)

    // 256 blocks: c = XCD, owns col-tiles c*2 and c*2+1
    const int c  = blockIdx.x & 7;
    const int j  = blockIdx.x >> 3;          // 0..31
    const int bn = (c * 2 + (j & 1)) * 384;
    const int bm = (j >> 1) * 256;

    // staging: 4 lanes/row (16B), 16 rows/wave/line; global col pre-swizzled
    const int rsub = wave * 16 + (lane >> 2);           // 0..191
    const int csw  = ((lane & 3) ^ ((lane >> 3) & 3)) * 8;
    const unsigned short* gA = A + (size_t)(bm + rsub) * lda + csw;
    const unsigned short* gB = W + (size_t)(bn + rsub) * ldw + csw;

    // A: rows 0-191 (12 waves) + rows 192-255 (waves 0-3); B: 2 x 192 rows
#define STAGE_A(ARR, kt) do { \
        gload16(gA + (kt) * 32, ARR + wave * 512); \
        if (wave < 4) gload16(gA + (size_t)192 * lda + (kt) * 32, ARR + 6144 + wave * 512); \
    } while (0)
#define STAGE_B(ARR, kt) do { \
        gload16(gB + (kt) * 32, ARR + wave * 512); \
        gload16(gB + (size_t)192 * ldw + (kt) * 32, ARR + 6144 + wave * 512); \
    } while (0)

    // frag reads: row*32 elems + (quad ^ ((row>>1)&3))*8; (row>>1)&3 == sw2
#define LDA_F(ARR, mi) \
    (*reinterpret_cast<const bf16x8*>(&ARR[(wr * 128 + (mi) * 16 + lr) * 32 + ((quad ^ sw2)) * 8]))
#define LDB_F(ARR, ni) \
    (*reinterpret_cast<const bf16x8*>(&ARR[(wcc * 64 + (ni) * 16 + lr) * 32 + ((quad ^ sw2)) * 8]))

#define PRIO1 __builtin_amdgcn_s_setprio(1)
#define PRIO0 __builtin_amdgcn_s_setprio(0)
#define VM0B  asm volatile("s_waitcnt vmcnt(0)\n\ts_barrier" ::: "memory")

    // body: fb[4] once, then 4 fa-pairs x 8 MFMA (acc liveness capped)
#define TILE_BODY(AX, BX) do { \
        _Pragma("unroll") for (int ni = 0; ni < 4; ++ni) fb[ni] = LDB_F(BX, ni); \
        _Pragma("unroll") for (int mp = 0; mp < 4; ++mp) { \
            bf16x8 fa0 = LDA_F(AX, 2 * mp); \
            bf16x8 fa1 = LDA_F(AX, 2 * mp + 1); \
            PRIO1; \
            _Pragma("unroll") for (int ni = 0; ni < 4; ++ni) { \
                acc[2 * mp][ni]     = __builtin_amdgcn_mfma_f32_16x16x32_bf16(fa0, fb[ni], acc[2 * mp][ni], 0, 0, 0); \
                acc[2 * mp + 1][ni] = __builtin_amdgcn_mfma_f32_16x16x32_bf16(fa1, fb[ni], acc[2 * mp + 1][ni], 0, 0, 0); } \
            PRIO0; } \
    } while (0)

    f32x4 acc[8][4];
    const f32x4 zero = {0.f, 0.f, 0.f, 0.f};
#pragma unroll
    for (int m = 0; m < 8; ++m)
#pragma unroll
        for (int n = 0; n < 4; ++n) acc[m][n] = zero;

    bf16x8 fb[4];

    const int nkt = Kc >> 5;   // 48 (even)

    STAGE_A(A0s, 0); STAGE_B(B0s, 0);
    VM0B;

#pragma unroll 1
    for (int t = 0; t < nkt; t += 2) {
        if (t + 1 < nkt) { STAGE_A(A1s, t + 1); STAGE_B(B1s, t + 1); }
        TILE_BODY(A0s, B0s);
        VM0B;
        if (t + 1 < nkt) {
            if (t + 2 < nkt) { STAGE_A(A0s, t + 2); STAGE_B(B0s, t + 2); }
            TILE_BODY(A1s, B1s);
            VM0B;
        }
    }

    // C-write: row = bm + wr*128 + mi*16 + quad*4 + reg; col = bn + wcc*64 + ni*16 + lr
#pragma unroll
    for (int mi = 0; mi < 8; ++mi) {
        const int row0 = bm + wr * 128 + mi * 16 + quad * 4;
#pragma unroll
        for (int ni = 0; ni < 4; ++ni) {
            const int col = bn + wcc * 64 + ni * 16 + lr;
#pragma unroll
            for (int reg = 0; reg < 4; ++reg) {
                float v = acc[mi][ni][reg];
                if (col >= silu_col0) v = silu_f(v);
                Cout[(size_t)(row0 + reg) * ldc + col] = f2b(v);
            }
        }
    }
#undef STAGE_A
#undef STAGE_B
#undef LDA_F
#undef LDB_F
#undef PRIO1
#undef PRIO0
#undef VM0B
#undef TILE_BODY
}

// ============================================================================
// out_proj GEMM v2: 128M x 192N tile, BK=64, grid 256 (one round), K=3072,
// fp32 direct to d_out; now 768 thr = 12 waves (2M x 6N, wave tile 64x32)
// -> 3 waves/SIMD.  acc[4][2]=32 VGPR (tiny).  LDS 80KB dbuf unchanged.
// Staging at 12 waves (128B rows, 8 lanes/row, 96 rows/line):
// A = 96-row line + 32-row remainder (waves 0-3); B = 2 x 96-row lines.
// ============================================================================
__global__ __launch_bounds__(768, 3)
void gemm_out(const unsigned short* __restrict__ A, const unsigned short* __restrict__ W,
              float* __restrict__ Cout, int Kc, int lda, int ldw, int ldc) {
    __shared__ __align__(16) unsigned short A0s[8192];    // 128x64 bf16
    __shared__ __align__(16) unsigned short B0s[12288];   // 192x64 bf16
    __shared__ __align__(16) unsigned short A1s[8192];
    __shared__ __align__(16) unsigned short B1s[12288];
    const int tid  = threadIdx.x;
    const int lane = tid & 63;
    const int wave = tid >> 6;     // 0..11
    const int wr   = wave / 6;     // 0..1 (64-row half)
    const int wcc  = wave % 6;     // 0..5 (32-col group)
    const int lr   = lane & 15;
    const int quad = lane >> 4;
    const int sw   = lr & 7;

    // grid 256 = 8 XCD col-stripes x 32 M-tiles
    const int c  = blockIdx.x & 7;
    const int j  = blockIdx.x >> 3;   // 0..31
    const int bm = j * 128;
    const int bn = c * 192;

    const int rsub = wave * 8 + (lane >> 3);            // 0..95
    const int csw  = ((lane & 7) ^ ((lane >> 3) & 7)) * 8;
    const unsigned short* gA = A + (size_t)(bm + rsub) * lda + csw;
    const unsigned short* gB = W + (size_t)(bn + rsub) * ldw + csw;

    // A: rows 0-95 (12 waves) + rows 96-127 (waves 0-3); B: 2 x 96-row lines
#define STAGE_A(ARR, kt) do { \
        gload16(gA + (kt) * 64, ARR + wave * 512); \
        if (wave < 4) gload16(gA + (size_t)96 * lda + (kt) * 64, ARR + 6144 + wave * 512); \
    } while (0)
#define STAGE_B(ARR, kt) do { \
        gload16(gB + (kt) * 64, ARR + wave * 512); \
        gload16(gB + (size_t)96 * ldw + (kt) * 64, ARR + 6144 + wave * 512); \
    } while (0)

#define LDA_F(ARR, mi, kk) \
    (*reinterpret_cast<const bf16x8*>(&ARR[(wr * 64 + (mi) * 16 + lr) * 64 + (((((kk) << 2) | quad)) ^ sw) * 8]))
#define LDB_F(ARR, ni, kk) \
    (*reinterpret_cast<const bf16x8*>(&ARR[(wcc * 32 + (ni) * 16 + lr) * 64 + (((((kk) << 2) | quad)) ^ sw) * 8]))

#define PRIO1 __builtin_amdgcn_s_setprio(1)
#define PRIO0 __builtin_amdgcn_s_setprio(0)
#define VM0B  asm volatile("s_waitcnt vmcnt(0)\n\ts_barrier" ::: "memory")

#define TILE_BODY(AX, BX) do { \
        _Pragma("unroll") for (int ni = 0; ni < 2; ++ni) { \
            fb[ni][0] = LDB_F(BX, ni, 0); fb[ni][1] = LDB_F(BX, ni, 1); } \
        _Pragma("unroll") for (int mi = 0; mi < 4; ++mi) { \
            fa[mi][0] = LDA_F(AX, mi, 0); fa[mi][1] = LDA_F(AX, mi, 1); } \
        PRIO1; \
        _Pragma("unroll") for (int mi = 0; mi < 4; ++mi) \
        _Pragma("unroll") for (int ni = 0; ni < 2; ++ni) { \
            acc[mi][ni] = __builtin_amdgcn_mfma_f32_16x16x32_bf16(fa[mi][0], fb[ni][0], acc[mi][ni], 0, 0, 0); \
            acc[mi][ni] = __builtin_amdgcn_mfma_f32_16x16x32_bf16(fa[mi][1], fb[ni][1], acc[mi][ni], 0, 0, 0); } \
        PRIO0; \
    } while (0)

    f32x4 acc[4][2];
    const f32x4 zero = {0.f, 0.f, 0.f, 0.f};
#pragma unroll
    for (int m = 0; m < 4; ++m) { acc[m][0] = zero; acc[m][1] = zero; }

    bf16x8 fa[4][2], fb[2][2];

    const int nkt = Kc >> 6;   // 48 (even)

    STAGE_A(A0s, 0); STAGE_B(B0s, 0);
    VM0B;

#pragma unroll 1
    for (int t = 0; t < nkt; t += 2) {
        if (t + 1 < nkt) { STAGE_A(A1s, t + 1); STAGE_B(B1s, t + 1); }
        TILE_BODY(A0s, B0s);
        VM0B;
        if (t + 1 < nkt) {
            if (t + 2 < nkt) { STAGE_A(A0s, t + 2); STAGE_B(B0s, t + 2); }
            TILE_BODY(A1s, B1s);
            VM0B;
        }
    }

    // C-write: row = bm + wr*64 + mi*16 + quad*4 + reg; col = bn + wcc*32 + ni*16 + lr
#pragma unroll
    for (int mi = 0; mi < 4; ++mi) {
        const int row0 = bm + wr * 64 + mi * 16 + quad * 4;
#pragma unroll
        for (int ni = 0; ni < 2; ++ni) {
            const int col = bn + wcc * 32 + ni * 16 + lr;
#pragma unroll
            for (int reg = 0; reg < 4; ++reg)
                Cout[(size_t)(row0 + reg) * ldc + col] = acc[mi][ni][reg];
        }
    }
#undef STAGE_A
#undef STAGE_B
#undef LDA_F
#undef LDB_F
#undef PRIO1
#undef PRIO0
#undef VM0B
#undef TILE_BODY
}

// ---------- MFMA GEMM, 3-stage pipelined async LDS staging (128x128) ----------
// kept for x_proj (N=128) and dt_proj (K=96).
// OP=0: fp32 store (+ split-K z, C offset kz*czs)
// OP=3: bf16 store of softplus(acc + bias[col])
template <int OP>
__global__ __launch_bounds__(256)
void gemm_mfma(const unsigned short* __restrict__ A, const unsigned short* __restrict__ W,
               void* __restrict__ Cout, int Kc, int lda, int ldw, int ldc,
               const float* __restrict__ bias, int silu_col0, long long czs) {
    __shared__ unsigned short As[3][4096];   // 3 x 128x32 bf16 = 24 KB
    __shared__ unsigned short Bs[3][4096];
    const int tid = threadIdx.x;
    const int bm = blockIdx.y * 128;
    const int bn = blockIdx.x * 128;
    const int kz = blockIdx.z;
    A += (size_t)kz * Kc;
    W += (size_t)kz * Kc;
    const int lane = tid & 63;
    const int wave = tid >> 6;
    const int r_a = lane >> 2;          // row within 16-row chunk
    const int k8 = (lane & 3) * 8;      // k offset (8 bf16 = 16B)

    const unsigned short* gA0 = A + (size_t)(bm + wave * 16 + r_a) * lda + k8;
    const unsigned short* gA1 = A + (size_t)(bm + 64 + wave * 16 + r_a) * lda + k8;
    const unsigned short* gB0 = W + (size_t)(bn + wave * 16 + r_a) * ldw + k8;
    const unsigned short* gB1 = W + (size_t)(bn + 64 + wave * 16 + r_a) * ldw + k8;

    const int wm = (wave & 1) * 64;
    const int wn = (wave >> 1) * 64;
    const int lr = lane & 15;
    const int quad = lane >> 4;

    f32x4 acc[4][4];
    const f32x4 zero = {0.f, 0.f, 0.f, 0.f};
#pragma unroll
    for (int i = 0; i < 4; i++)
#pragma unroll
        for (int j = 0; j < 4; j++) acc[i][j] = zero;

#define STAGE(koff, j) do { \
        gload16(gA0 + (koff), As[j] + wave * 512); \
        gload16(gA1 + (koff), As[j] + (wave + 4) * 512); \
        gload16(gB0 + (koff), Bs[j] + wave * 512); \
        gload16(gB1 + (koff), Bs[j] + (wave + 4) * 512); \
    } while (0)

    const int niter = Kc >> 5;
    STAGE(0, 0);
    if (niter > 1) STAGE(32, 1);

    int ib = 0;   // LDS buffer holding tile k
    for (int k = 0; k < niter; k++) {
        if (k + 1 < niter)
            asm volatile("s_waitcnt vmcnt(4)\n\ts_barrier" ::: "memory");
        else
            asm volatile("s_waitcnt vmcnt(0)\n\ts_barrier" ::: "memory");
        if (k + 2 < niter) {
            int is_ = ib + 2; if (is_ >= 3) is_ -= 3;
            STAGE((k + 2) << 5, is_);
        }
        const unsigned short* as = As[ib];
        const unsigned short* bs = Bs[ib];
        bf16x8 fa[4], fb[4];
#pragma unroll
        for (int mi = 0; mi < 4; mi++)
            fa[mi] = *reinterpret_cast<const bf16x8*>(as + (wm + mi * 16 + lr) * 32 + quad * 8);
#pragma unroll
        for (int ni = 0; ni < 4; ni++)
            fb[ni] = *reinterpret_cast<const bf16x8*>(bs + (wn + ni * 16 + lr) * 32 + quad * 8);
#pragma unroll
        for (int mi = 0; mi < 4; mi++)
#pragma unroll
            for (int ni = 0; ni < 4; ni++)
                acc[mi][ni] = __builtin_amdgcn_mfma_f32_16x16x32_bf16(fa[mi], fb[ni], acc[mi][ni], 0, 0, 0);
        ib = (ib == 2) ? 0 : ib + 1;
    }
#undef STAGE

    // C/D layout: col = lane&15 (+16*ni), row = quad*4 + reg (+16*mi)
#pragma unroll
    for (int mi = 0; mi < 4; mi++)
#pragma unroll
        for (int reg = 0; reg < 4; reg++) {
            int row = bm + wm + mi * 16 + quad * 4 + reg;
#pragma unroll
            for (int ni = 0; ni < 4; ni++) {
                int col = bn + wn + ni * 16 + lr;
                float v = acc[mi][ni][reg];
                if (OP == 0) {
                    float* Cf = (float*)Cout + (size_t)kz * czs;
                    Cf[(size_t)row * ldc + col] = v;
                } else if (OP == 2) {
                    if (col >= silu_col0) v = silu_f(v);
                    ((unsigned short*)Cout)[(size_t)row * ldc + col] = f2b(v);
                } else {  // OP == 3
                    ((unsigned short*)Cout)[(size_t)row * ldc + col] = f2b(softplus_f(v + bias[col]));
                }
            }
        }
}

// ---------- split-K reduction for x_proj; fuses dtin bf16 extraction ----------
__global__ __launch_bounds__(256)
void reduce_xpart(const float* __restrict__ xpart, float* __restrict__ ssmp,
                  unsigned short* __restrict__ dtin) {
    const int BL = 4096;
    int idx = blockIdx.x * 256 + threadIdx.x;   // BL*32 threads
    int row = idx >> 5;
    int c4 = (idx & 31) * 4;
    float4 s = {0.f, 0.f, 0.f, 0.f};
#pragma unroll
    for (int z = 0; z < 8; z++) {
        float4 v = *reinterpret_cast<const float4*>(xpart + (size_t)z * BL * 128 + (size_t)row * 128 + c4);
        s.x += v.x; s.y += v.y; s.z += v.z; s.w += v.w;
    }
    *reinterpret_cast<float4*>(ssmp + (size_t)row * 128 + c4) = s;
    if (c4 < 96) {
        ushort4 o;
        o.x = f2b(s.x); o.y = f2b(s.y); o.z = f2b(s.z); o.w = f2b(s.w);
        *reinterpret_cast<ushort4*>(dtin + (size_t)row * 96 + c4) = o;
    }
}

// ---------- causal depthwise conv (K=4) + SiLU, 8 channels/thread ----------
__global__ __launch_bounds__(256)
void conv_silu8(const unsigned short* __restrict__ projbf, const float* __restrict__ cw,
                const float* __restrict__ cb, unsigned short* __restrict__ xc) {
    const int I = 3072, L = 2048, LD = 6144;
    int idx = blockIdx.x * 256 + threadIdx.x;    // over BL*I/8
    int i8 = (idx % (I / 8)) * 8;
    int bl = idx / (I / 8);
    int l = bl & (L - 1);
    float s[8];
    {
        float4 b0 = *reinterpret_cast<const float4*>(cb + i8);
        float4 b1 = *reinterpret_cast<const float4*>(cb + i8 + 4);
        s[0]=b0.x; s[1]=b0.y; s[2]=b0.z; s[3]=b0.w; s[4]=b1.x; s[5]=b1.y; s[6]=b1.z; s[7]=b1.w;
    }
    float w[8][4];
#pragma unroll
    for (int c = 0; c < 8; c++) {
        float4 wr = *reinterpret_cast<const float4*>(cw + (i8 + c) * 4);
        w[c][0]=wr.x; w[c][1]=wr.y; w[c][2]=wr.z; w[c][3]=wr.w;
    }
#pragma unroll
    for (int j = 0; j < 4; j++) {
        if (l + j - 3 >= 0) {
            uint4 r = *reinterpret_cast<const uint4*>(projbf + (size_t)(bl + j - 3) * LD + i8);
            float xv[8];
            xv[0]=b2f((unsigned short)(r.x & 0xffff)); xv[1]=b2f((unsigned short)(r.x >> 16));
            xv[2]=b2f((unsigned short)(r.y & 0xffff)); xv[3]=b2f((unsigned short)(r.y >> 16));
            xv[4]=b2f((unsigned short)(r.z & 0xffff)); xv[5]=b2f((unsigned short)(r.z >> 16));
            xv[6]=b2f((unsigned short)(r.w & 0xffff)); xv[7]=b2f((unsigned short)(r.w >> 16));
#pragma unroll
            for (int c = 0; c < 8; c++) s[c] = fmaf(xv[c], w[c][j], s[c]);
        }
    }
    unsigned short o[8];
#pragma unroll
    for (int c = 0; c < 8; c++) o[c] = f2b(silu_f(s[c]));
    uint4 packed;
    packed.x = (unsigned)o[0] | ((unsigned)o[1] << 16);
    packed.y = (unsigned)o[2] | ((unsigned)o[3] << 16);
    packed.z = (unsigned)o[4] | ((unsigned)o[5] << 16);
    packed.w = (unsigned)o[6] | ((unsigned)o[7] << 16);
    *reinterpret_cast<uint4*>(xc + (size_t)bl * I + i8) = packed;
}

// ---------- pass A: per-chunk local scan (init 0) -> S_local, sumDelta ----------
__global__ __launch_bounds__(256)
void scan_passA(const unsigned short* __restrict__ delta_bf, const unsigned short* __restrict__ xc,
                const float* __restrict__ ssmp, const float* __restrict__ Aw,
                float* __restrict__ S_local, float* __restrict__ sumDelta) {
    const int I = 3072, L = 2048;
    __shared__ float bc[TCH][32];
    int g = blockIdx.x * 256 + threadIdx.x;
    int i = g % I;
    int bcid = g / I;
    int c = bcid % CCH;
    int b = bcid / CCH;
    size_t rowbase = (size_t)b * L + (size_t)c * TCH;
    for (int e = threadIdx.x; e < TCH * 8; e += 256) {
        int t = e >> 3, q = e & 7;
        float4 v = *reinterpret_cast<const float4*>(ssmp + (rowbase + t) * 128 + 96 + q * 4);
        *reinterpret_cast<float4*>(&bc[t][q * 4]) = v;
    }
    __syncthreads();

    float Arow[16];
#pragma unroll
    for (int n = 0; n < 16; n++) Arow[n] = Aw[i * 16 + n];
    float st[16];
#pragma unroll
    for (int n = 0; n < 16; n++) st[n] = 0.f;
    float sumD = 0.f;

    size_t rowI = rowbase * I + i;
    for (int t = 0; t < TCH; t++) {
        float delta = b2f(delta_bf[rowI]);
        float du = delta * b2f(xc[rowI]);
        sumD += delta;
        float4 b0 = *reinterpret_cast<const float4*>(&bc[t][0]);
        float4 b1 = *reinterpret_cast<const float4*>(&bc[t][4]);
        float4 b2 = *reinterpret_cast<const float4*>(&bc[t][8]);
        float4 b3 = *reinterpret_cast<const float4*>(&bc[t][12]);
        const float bv[16] = {b0.x,b0.y,b0.z,b0.w, b1.x,b1.y,b1.z,b1.w,
                              b2.x,b2.y,b2.z,b2.w, b3.x,b3.y,b3.z,b3.w};
#pragma unroll
        for (int n = 0; n < 16; n++)
            st[n] = fmaf(st[n], __expf(delta * Arow[n]), du * bv[n]);
        rowI += I;
    }
    size_t obase = (size_t)bcid * 16 * I + i;
#pragma unroll
    for (int n = 0; n < 16; n++) S_local[obase + (size_t)n * I] = st[n];
    sumDelta[(size_t)bcid * I + i] = sumD;
}

// ---------- pass B: sequential combine across chunks -> state_in ----------
__global__ __launch_bounds__(256)
void scan_passB(const float* __restrict__ S_local, const float* __restrict__ sumDelta,
                const float* __restrict__ Aw, float* __restrict__ state_in) {
    const int I = 3072;
    int g = blockIdx.x * 256 + threadIdx.x;
    int i = g % I;
    int bn = g / I;
    int n = bn & 15;
    int b = bn >> 4;
    float a = Aw[i * 16 + n];
    float state = 0.f;
    for (int c = 0; c < CCH; c++) {
        int bcid = b * CCH + c;
        size_t idx = ((size_t)bcid * 16 + n) * I + i;
        state_in[idx] = state;
        state = fmaf(state, __expf(a * sumDelta[(size_t)bcid * I + i]), S_local[idx]);
    }
}

// ---------- pass C: re-scan from state_in; fused y, D-skip, pre-silu'd gate ----------
__global__ __launch_bounds__(256)
void scan_passC(const unsigned short* __restrict__ projbf,   // silu(gate) at col 3072+i, ld 6144
                const unsigned short* __restrict__ xc,
                const float* __restrict__ ssmp, const unsigned short* __restrict__ delta_bf,
                const float* __restrict__ Aw, const float* __restrict__ Dw,
                const float* __restrict__ state_in, unsigned short* __restrict__ ybf) {
    const int I = 3072, L = 2048, LD = 6144;
    __shared__ float bc[TCH][32];
    int g = blockIdx.x * 256 + threadIdx.x;
    int i = g % I;
    int bcid = g / I;
    int c = bcid % CCH;
    int b = bcid / CCH;
    size_t rowbase = (size_t)b * L + (size_t)c * TCH;
    for (int e = threadIdx.x; e < TCH * 8; e += 256) {
        int t = e >> 3, q = e & 7;
        float4 v = *reinterpret_cast<const float4*>(ssmp + (rowbase + t) * 128 + 96 + q * 4);
        *reinterpret_cast<float4*>(&bc[t][q * 4]) = v;
    }
    __syncthreads();

    float Arow[16];
#pragma unroll
    for (int n = 0; n < 16; n++) Arow[n] = Aw[i * 16 + n];
    float Dv = Dw[i];
    float st[16];
    size_t sbase = (size_t)bcid * 16 * I + i;
#pragma unroll
    for (int n = 0; n < 16; n++) st[n] = state_in[sbase + (size_t)n * I];

    size_t rowI = rowbase * I + i;
    size_t rowG = rowbase * LD + I + i;
    for (int t = 0; t < TCH; t++) {
        float delta = b2f(delta_bf[rowI]);
        float u = b2f(xc[rowI]);
        float du = delta * u;
        float4 b0 = *reinterpret_cast<const float4*>(&bc[t][0]);
        float4 b1 = *reinterpret_cast<const float4*>(&bc[t][4]);
        float4 b2 = *reinterpret_cast<const float4*>(&bc[t][8]);
        float4 b3 = *reinterpret_cast<const float4*>(&bc[t][12]);
        float4 c0 = *reinterpret_cast<const float4*>(&bc[t][16]);
        float4 c1 = *reinterpret_cast<const float4*>(&bc[t][20]);
        float4 c2 = *reinterpret_cast<const float4*>(&bc[t][24]);
        float4 c3 = *reinterpret_cast<const float4*>(&bc[t][28]);
        const float bv[16] = {b0.x,b0.y,b0.z,b0.w, b1.x,b1.y,b1.z,b1.w,
                              b2.x,b2.y,b2.z,b2.w, b3.x,b3.y,b3.z,b3.w};
        const float cv[16] = {c0.x,c0.y,c0.z,c0.w, c1.x,c1.y,c1.z,c1.w,
                              c2.x,c2.y,c2.z,c2.w, c3.x,c3.y,c3.z,c3.w};
        float y = 0.f;
#pragma unroll
        for (int n = 0; n < 16; n++) {
            st[n] = fmaf(st[n], __expf(delta * Arow[n]), du * bv[n]);
            y = fmaf(st[n], cv[n], y);
        }
        y = fmaf(u, Dv, y);
        y *= b2f(projbf[rowG]);            // gate already silu'd in GEMM epilogue
        ybf[rowI] = f2b(y);
        rowI += I;
        rowG += LD;
    }
}

extern "C" void kernel_launch(void* const* d_in, const int* in_sizes, int n_in,
                              void* d_out, int out_size, void* d_ws, size_t ws_size,
                              hipStream_t stream) {
    const float* hidden  = (const float*)d_in[0];
    const float* W_in    = (const float*)d_in[1];
    const float* conv_w  = (const float*)d_in[2];
    const float* conv_b  = (const float*)d_in[3];
    const float* W_x     = (const float*)d_in[4];
    const float* W_dt    = (const float*)d_in[5];
    const float* dt_bias = (const float*)d_in[6];
    const float* Aw      = (const float*)d_in[7];
    const float* Dw      = (const float*)d_in[8];
    const float* W_out   = (const float*)d_in[9];
    float* out = (float*)d_out;

    constexpr int Bsz = 2, L = 2048, H = 1536, I = 3072, R = 96;
    constexpr int BL = Bsz * L;        // 4096
    constexpr int TwoI = 2 * I;        // 6144

    // ---- workspace layout ----
    char* base = (char*)d_ws;
    unsigned short* proj_bf  = (unsigned short*)base; base += (size_t)BL * TwoI * 2;   // 50.3 MB
    unsigned short* delta_bf = (unsigned short*)base; base += (size_t)BL * I * 2;      // 25.2 MB
    unsigned short* xc_bf    = (unsigned short*)base; base += (size_t)BL * I * 2;      // 25.2 MB
    unsigned short* y_bf     = (unsigned short*)base; base += (size_t)BL * I * 2;      // 25.2 MB
    float* ssmp              = (float*)base;          base += (size_t)BL * 128 * 4;    // 2.1 MB
    float* xpart             = (float*)base;          base += (size_t)8 * BL * 128 * 4;// 16.8 MB
    unsigned short* dtin_bf  = (unsigned short*)base; base += (size_t)BL * R * 2;      // 0.8 MB
    unsigned short* wx_bf    = (unsigned short*)base; base += (size_t)128 * I * 2;     // 0.8 MB
    unsigned short* wdt_bf   = (unsigned short*)base; base += (size_t)I * R * 2;       // 0.6 MB
    unsigned short* wout_bf  = (unsigned short*)base; base += (size_t)H * I * 2;       // 9.4 MB
    unsigned short* h_bf     = (unsigned short*)base; base += (size_t)BL * H * 2;      // 12.6 MB
    unsigned short* win_bf   = (unsigned short*)base; base += (size_t)TwoI * H * 2;    // 18.9 MB
    // scan scratch overlays h_bf+win_bf (dead after in_proj): 26.0 <= 31.5 MB
    float* S_local  = (float*)h_bf;
    float* sumDelta = S_local + (size_t)Bsz * CCH * 16 * I;
    float* state_in = sumDelta + (size_t)Bsz * CCH * I;

    dim3 blk(256);

    // 0) fused weight/act casts
    cast_all<<<(5283840 + 255) / 256, blk, 0, stream>>>(
        hidden, W_in, W_x, W_dt, W_out, h_bf, win_bf, wx_bf, wdt_bf, wout_bf);

    // 1) in_proj -> proj_bf [4096,6144] bf16; silu on gate half (cols >= 3072)
    //    256x384 tiles, 12 waves (3/SIMD), grid EXACTLY 256 (one round)
    gemm_in<<<dim3(256, 1, 1), dim3(768), 0, stream>>>(
        h_bf, win_bf, proj_bf, H, H, H, TwoI, /*silu*/ I);

    // 2) causal conv + SiLU -> xc_bf
    conv_silu8<<<BL * I / 8 / 256, blk, 0, stream>>>(proj_bf, conv_w, conv_b, xc_bf);

    // 3) x_proj split-K x8: xpart[z][4096][128] = xc @ wx^T (K chunk 384)
    gemm_mfma<0><<<dim3(1, BL / 128, 8), blk, 0, stream>>>(
        xc_bf, wx_bf, xpart, I / 8, I, I, 128, nullptr, 0, (long long)BL * 128);
    reduce_xpart<<<BL * 32 / 256, blk, 0, stream>>>(xpart, ssmp, dtin_bf);

    // 4) dt_proj, fused +bias & softplus -> delta_bf [4096,3072] bf16
    gemm_mfma<3><<<dim3(I / 128, BL / 128, 1), blk, 0, stream>>>(
        dtin_bf, wdt_bf, delta_bf, R, R, R, I, dt_bias, 0, 0);

    // 5) chunk-parallel selective scan
    scan_passA<<<Bsz * I * CCH / 256, blk, 0, stream>>>(
        delta_bf, xc_bf, ssmp, Aw, S_local, sumDelta);
    scan_passB<<<Bsz * 16 * I / 256, blk, 0, stream>>>(
        S_local, sumDelta, Aw, state_in);
    scan_passC<<<Bsz * I * CCH / 256, blk, 0, stream>>>(
        proj_bf, xc_bf, ssmp, delta_bf, Aw, Dw, state_in, y_bf);

    // 6) out_proj: 128x192 tiles, 12 waves (3/SIMD), grid EXACTLY 256,
    //    fp32 direct to out
    gemm_out<<<dim3(256, 1, 1), dim3(768), 0, stream>>>(
        y_bf, wout_bf, out, I, I, I, H);
}